// Round 1
// baseline (926.692 us; speedup 1.0000x reference)
//
#include <hip/hip_runtime.h>

typedef __attribute__((ext_vector_type(8))) short s8x;   // 8 x bf16 (raw bits)
typedef __attribute__((ext_vector_type(4))) float f4x;
typedef unsigned short u16;
typedef unsigned int u32;

#define DEV static __device__ __forceinline__

DEV u16 f2b(float f) {
    union { float f; u32 u; } v; v.f = f;
    u32 r = v.u + 0x7FFFu + ((v.u >> 16) & 1u);
    return (u16)(r >> 16);
}

DEV void gload16(const void* g, void* lds) {
    __builtin_amdgcn_global_load_lds(
        (const __attribute__((address_space(1))) void*)g,
        (__attribute__((address_space(3))) void*)lds, 16, 0, 0);
}

// ---------------- GEMM: C[M,N] = A[M,K] @ W[N,K]^T + bias, fused epilogue ----------------
// M=8192, N=1024, K=1024 fixed. 128x128 tile, BK=64, 256 threads (4 waves, 2x2), 2-phase dbuf.
#define GM 8192
#define GN 1024
#define GK 1024
#define BM 128
#define BN 128
#define BK 64

template<int FLAGS>
__global__ __launch_bounds__(256) void gemm_bt(
    const u16* __restrict__ A, const u16* __restrict__ W,
    const float* __restrict__ bias, const float* __restrict__ res,
    float* __restrict__ outf, u16* __restrict__ outb)
{
    constexpr bool RELU = (FLAGS & 1) != 0;
    constexpr bool RES  = (FLAGS & 2) != 0;
    constexpr bool WF   = (FLAGS & 4) != 0;
    constexpr bool WB   = (FLAGS & 8) != 0;

    __shared__ __attribute__((aligned(16))) u16 As[2][BM * BK];
    __shared__ __attribute__((aligned(16))) u16 Bs[2][BN * BK];

    const int tid  = threadIdx.x;
    const int lane = tid & 63;
    const int wid  = tid >> 6;
    const int wr = wid >> 1, wc = wid & 1;
    const int bm = blockIdx.x, bn = blockIdx.y;
    const int l15 = lane & 15;
    const int lg  = lane >> 4;

    const u16* Ab = A + (size_t)bm * BM * GK;
    const u16* Wb = W + (size_t)bn * BN * GK;

    const int prow = tid >> 3;          // 0..31, +32 per staging call
    const int pcol = (tid & 7) * 8;     // element col within BK

    f4x acc[4][4];
#pragma unroll
    for (int i = 0; i < 4; ++i)
#pragma unroll
        for (int j = 0; j < 4; ++j) { f4x z = {0.f, 0.f, 0.f, 0.f}; acc[i][j] = z; }

    // prologue: stage kt=0 into buf0
#pragma unroll
    for (int c = 0; c < 4; ++c) {
        int row = c * 32 + prow;
        gload16(Ab + (size_t)row * GK + pcol, &As[0][row * BK + pcol]);
    }
#pragma unroll
    for (int c = 0; c < 4; ++c) {
        int row = c * 32 + prow;
        gload16(Wb + (size_t)row * GK + pcol, &Bs[0][row * BK + pcol]);
    }

    const int nkt = GK / BK;
    int cur = 0;
    for (int kt = 0; kt < nkt; ++kt) {
        __syncthreads();   // buf[cur] staged (vmcnt drained); prev compute on buf[cur^1] done
        if (kt + 1 < nkt) {
            const u16* Ak = Ab + (kt + 1) * BK;
            const u16* Wk = Wb + (kt + 1) * BK;
#pragma unroll
            for (int c = 0; c < 4; ++c) {
                int row = c * 32 + prow;
                gload16(Ak + (size_t)row * GK + pcol, &As[cur ^ 1][row * BK + pcol]);
            }
#pragma unroll
            for (int c = 0; c < 4; ++c) {
                int row = c * 32 + prow;
                gload16(Wk + (size_t)row * GK + pcol, &Bs[cur ^ 1][row * BK + pcol]);
            }
        }
        const u16* Ac = As[cur];
        const u16* Bc = Bs[cur];
#pragma unroll
        for (int kk = 0; kk < 2; ++kk) {
            s8x a[4], b[4];
#pragma unroll
            for (int mi = 0; mi < 4; ++mi)
                a[mi] = *(const s8x*)(Ac + (wr * 64 + mi * 16 + l15) * BK + kk * 32 + lg * 8);
#pragma unroll
            for (int ni = 0; ni < 4; ++ni)
                b[ni] = *(const s8x*)(Bc + (wc * 64 + ni * 16 + l15) * BK + kk * 32 + lg * 8);
#pragma unroll
            for (int mi = 0; mi < 4; ++mi)
#pragma unroll
                for (int ni = 0; ni < 4; ++ni)
                    acc[mi][ni] = __builtin_amdgcn_mfma_f32_16x16x32_bf16(a[mi], b[ni], acc[mi][ni], 0, 0, 0);
        }
        cur ^= 1;
    }

    // epilogue: C/D layout col=lane&15, row=(lane>>4)*4+r
#pragma unroll
    for (int ni = 0; ni < 4; ++ni) {
        int gcol = bn * BN + wc * 64 + ni * 16 + l15;
        float bv = bias[gcol];
#pragma unroll
        for (int mi = 0; mi < 4; ++mi) {
            int grow0 = bm * BM + wr * 64 + mi * 16 + lg * 4;
#pragma unroll
            for (int r = 0; r < 4; ++r) {
                float v = acc[mi][ni][r] + bv;
                if (RELU) v = fmaxf(v, 0.f);
                size_t oidx = (size_t)(grow0 + r) * GN + gcol;
                if (RES) v += res[oidx];
                if (WF) outf[oidx] = v;
                if (WB) outb[oidx] = f2b(v);
            }
        }
    }
}

// ---------------- Attention: flash-style, 64 q-rows/block, heads=16, DK=64, S=1024 ----------------
__global__ __launch_bounds__(256) void attn_kernel(
    const u16* __restrict__ Qm, const u16* __restrict__ Km, const u16* __restrict__ Vm,
    const u32* __restrict__ maskw, const u32* __restrict__ rowfl,
    u16* __restrict__ Om)
{
    const int qt = blockIdx.x;   // 0..15 (q tile of 64)
    const int h  = blockIdx.y;   // 0..15
    const int b  = blockIdx.z;   // 0..7
    const int tid = threadIdx.x, lane = tid & 63, wid = tid >> 6;
    const int l15 = lane & 15, lg = lane >> 4;

    __shared__ __attribute__((aligned(16))) u16 Vt[64][72];      // V^T, padded (conflict-light)
    __shared__ __attribute__((aligned(16))) u16 Ps[4][16][72];   // per-wave P staging
    __shared__ int anymask;

    const size_t rowbase = (size_t)b * 1024;   // b*S
    const int hoff = h * 64;

    if (tid == 0) anymask = 0;
    __syncthreads();
    if (tid < 64) {
        if (rowfl[rowbase + qt * 64 + tid]) atomicOr(&anymask, 1);
    }

    // persistent Q fragments: wave owns q-rows wid*16..+16
    const int qrow = qt * 64 + wid * 16 + l15;
    s8x qf[2];
#pragma unroll
    for (int kk = 0; kk < 2; ++kk)
        qf[kk] = *(const s8x*)(Qm + (rowbase + qrow) * 1024 + hoff + kk * 32 + lg * 8);

    f4x o[4];
#pragma unroll
    for (int d = 0; d < 4; ++d) { f4x z = {0.f, 0.f, 0.f, 0.f}; o[d] = z; }
    float mrun[4], lrun[4];
#pragma unroll
    for (int r = 0; r < 4; ++r) { mrun[r] = -1e30f; lrun[r] = 0.f; }

    __syncthreads();
    const int am = anymask;

    for (int kt = 0; kt < 16; ++kt) {
        __syncthreads();   // previous tile's PV reads of Vt complete
        // stage V^T: wave w writes d-columns c=w and c=w+4; lane = v-row (conflict-free b16 writes)
#pragma unroll
        for (int it = 0; it < 2; ++it) {
            int c = wid + 4 * it;
            s8x vv = *(const s8x*)(Vm + (rowbase + kt * 64 + lane) * 1024 + hoff + c * 8);
#pragma unroll
            for (int j = 0; j < 8; ++j)
                Vt[c * 8 + j][lane] = (u16)vv[j];
        }

        // QK^T: K-fragments straight from global (L1-resident head panel)
        f4x sc[4];
#pragma unroll
        for (int ni = 0; ni < 4; ++ni) {
            f4x s = {0.f, 0.f, 0.f, 0.f};
#pragma unroll
            for (int kk = 0; kk < 2; ++kk) {
                s8x kf = *(const s8x*)(Km + (rowbase + kt * 64 + ni * 16 + l15) * 1024 + hoff + kk * 32 + lg * 8);
                s = __builtin_amdgcn_mfma_f32_16x16x32_bf16(qf[kk], kf, s, 0, 0, 0);
            }
            sc[ni] = s;
        }
        // scale + clip (+ mask)
#pragma unroll
        for (int ni = 0; ni < 4; ++ni)
#pragma unroll
            for (int r = 0; r < 4; ++r) {
                float v = sc[ni][r] * 0.125f;
                sc[ni][r] = fminf(fmaxf(v, -30.f), 30.f);
            }
        if (am) {
#pragma unroll
            for (int ni = 0; ni < 4; ++ni) {
                int kcol = kt * 64 + ni * 16 + l15;
#pragma unroll
                for (int r = 0; r < 4; ++r) {
                    int qr = qt * 64 + wid * 16 + lg * 4 + r;
                    u32 wb_ = maskw[(rowbase + qr) * 32 + (kcol >> 5)];
                    if (wb_ & (1u << (kcol & 31))) sc[ni][r] = -1e9f;
                }
            }
        }
        // online softmax (rows live in 16-lane groups; xor-reduce 8/4/2/1)
        float alpha[4];
#pragma unroll
        for (int r = 0; r < 4; ++r) {
            float mx = fmaxf(fmaxf(sc[0][r], sc[1][r]), fmaxf(sc[2][r], sc[3][r]));
            mx = fmaxf(mx, __shfl_xor(mx, 8));
            mx = fmaxf(mx, __shfl_xor(mx, 4));
            mx = fmaxf(mx, __shfl_xor(mx, 2));
            mx = fmaxf(mx, __shfl_xor(mx, 1));
            float mn = fmaxf(mrun[r], mx);
            alpha[r] = __expf(mrun[r] - mn);
            mrun[r] = mn;
        }
#pragma unroll
        for (int r = 0; r < 4; ++r) {
            float s = 0.f;
#pragma unroll
            for (int ni = 0; ni < 4; ++ni) {
                float p = __expf(sc[ni][r] - mrun[r]);
                sc[ni][r] = p;
                s += p;
            }
            s += __shfl_xor(s, 8); s += __shfl_xor(s, 4);
            s += __shfl_xor(s, 2); s += __shfl_xor(s, 1);
            lrun[r] = lrun[r] * alpha[r] + s;
        }
#pragma unroll
        for (int d = 0; d < 4; ++d)
#pragma unroll
            for (int r = 0; r < 4; ++r)
                o[d][r] *= alpha[r];

        // P: C/D layout -> A-frag layout via per-wave LDS round-trip
#pragma unroll
        for (int ni = 0; ni < 4; ++ni)
#pragma unroll
            for (int r = 0; r < 4; ++r)
                Ps[wid][lg * 4 + r][ni * 16 + l15] = f2b(sc[ni][r]);
        s8x pa[2];
#pragma unroll
        for (int kk = 0; kk < 2; ++kk)
            pa[kk] = *(const s8x*)(&Ps[wid][l15][kk * 32 + lg * 8]);

        __syncthreads();   // Vt staged by all waves
#pragma unroll
        for (int d = 0; d < 4; ++d) {
#pragma unroll
            for (int kk = 0; kk < 2; ++kk) {
                s8x vf = *(const s8x*)(&Vt[d * 16 + l15][kk * 32 + lg * 8]);
                o[d] = __builtin_amdgcn_mfma_f32_16x16x32_bf16(pa[kk], vf, o[d], 0, 0, 0);
            }
        }
    }

    // epilogue
    float rl[4];
#pragma unroll
    for (int r = 0; r < 4; ++r) rl[r] = 1.f / lrun[r];
#pragma unroll
    for (int d = 0; d < 4; ++d) {
        int gc = hoff + d * 16 + l15;
#pragma unroll
        for (int r = 0; r < 4; ++r) {
            int gr = qt * 64 + wid * 16 + lg * 4 + r;
            Om[(rowbase + gr) * 1024 + gc] = f2b(o[d][r] * rl[r]);
        }
    }
}

// ---------------- LayerNorm over D=1024, one wave per row, dual bf16/f32 output ----------------
__global__ __launch_bounds__(256) void ln_kernel(
    const float* __restrict__ x, const float* __restrict__ g, const float* __restrict__ bb,
    u16* __restrict__ yb, float* __restrict__ yf)
{
    const int wid = threadIdx.x >> 6, lane = threadIdx.x & 63;
    const size_t row = (size_t)blockIdx.x * 4 + wid;
    const float* xr = x + row * 1024;
    float4 v[4];
    float s = 0.f, s2 = 0.f;
#pragma unroll
    for (int c = 0; c < 4; ++c) {
        v[c] = *(const float4*)(xr + c * 256 + lane * 4);
        s  += v[c].x + v[c].y + v[c].z + v[c].w;
        s2 += v[c].x * v[c].x + v[c].y * v[c].y + v[c].z * v[c].z + v[c].w * v[c].w;
    }
#pragma unroll
    for (int m = 32; m >= 1; m >>= 1) { s += __shfl_xor(s, m); s2 += __shfl_xor(s2, m); }
    float mean = s * (1.f / 1024.f);
    float var  = s2 * (1.f / 1024.f) - mean * mean;
    float rs = rsqrtf(var + 1e-8f);
#pragma unroll
    for (int c = 0; c < 4; ++c) {
        int col = c * 256 + lane * 4;
        float4 gv = *(const float4*)(g + col);
        float4 bv = *(const float4*)(bb + col);
        float y0 = (v[c].x - mean) * rs * gv.x + bv.x;
        float y1 = (v[c].y - mean) * rs * gv.y + bv.y;
        float y2 = (v[c].z - mean) * rs * gv.z + bv.z;
        float y3 = (v[c].w - mean) * rs * gv.w + bv.w;
        if (yb) { ushort4 o4 = make_ushort4(f2b(y0), f2b(y1), f2b(y2), f2b(y3));
                  *(ushort4*)(yb + row * 1024 + col) = o4; }
        if (yf) { float4 o4f = make_float4(y0, y1, y2, y3);
                  *(float4*)(yf + row * 1024 + col) = o4f; }
    }
}

// ---------------- f32 -> bf16 convert ----------------
__global__ __launch_bounds__(256) void cvt_kernel(const float* __restrict__ x, u16* __restrict__ y, int n4)
{
    int i = blockIdx.x * 256 + threadIdx.x;
    if (i < n4) {
        float4 v = *(const float4*)(x + (size_t)i * 4);
        ushort4 o = make_ushort4(f2b(v.x), f2b(v.y), f2b(v.z), f2b(v.w));
        *(ushort4*)(y + (size_t)i * 4) = o;
    }
}

// ---------------- mask bitpack + per-row any-flag ----------------
__global__ __launch_bounds__(256) void mask_kernel(const int* __restrict__ am, u32* __restrict__ mw)
{
    size_t idx = (size_t)blockIdx.x * 256 + threadIdx.x;
    unsigned long long bal = __ballot(am[idx] == 0);
    int lane = threadIdx.x & 63;
    if (lane == 0)  mw[idx >> 5] = (u32)bal;
    if (lane == 32) mw[idx >> 5] = (u32)(bal >> 32);
}

__global__ __launch_bounds__(256) void rowflag_kernel(const u32* __restrict__ mw, u32* __restrict__ rf)
{
    int r = blockIdx.x * 256 + threadIdx.x;   // 8192 rows
    u32 o = 0;
#pragma unroll
    for (int i = 0; i < 32; ++i) o |= mw[r * 32 + i];
    rf[r] = o;
}

// ---------------- host-side orchestration ----------------
extern "C" void kernel_launch(void* const* d_in, const int* in_sizes, int n_in,
                              void* d_out, int out_size, void* d_ws, size_t ws_size,
                              hipStream_t stream)
{
    (void)in_sizes; (void)n_in; (void)out_size; (void)ws_size;

    const float* q_in  = (const float*)d_in[0];
    const float* k_in  = (const float*)d_in[1];
    const float* v_in  = (const float*)d_in[2];
    const int*   amask = (const int*)d_in[3];
    const float* Wqkv  = (const float*)d_in[4];
    const float* bqkv  = (const float*)d_in[5];
    const float* Wo    = (const float*)d_in[6];
    const float* bo    = (const float*)d_in[7];
    const float* ln1g  = (const float*)d_in[8];
    const float* ln1b  = (const float*)d_in[9];
    const float* ln2g  = (const float*)d_in[10];
    const float* ln2b  = (const float*)d_in[11];
    const float* Wc1   = (const float*)d_in[12];
    const float* bc1   = (const float*)d_in[13];
    const float* Wc2   = (const float*)d_in[14];
    const float* bc2   = (const float*)d_in[15];
    const float* lastg = (const float*)d_in[16];
    const float* lastb = (const float*)d_in[17];
    const float* Wfc   = (const float*)d_in[18];
    const float* bfc   = (const float*)d_in[19];
    float* out = (float*)d_out;

    char* base = (char*)d_ws;
    size_t off = 0;
    auto alloc = [&](size_t bytes) -> char* {
        char* p = base + off;
        off = (off + bytes + 255) & ~(size_t)255;
        return p;
    };
    const size_t M1 = 1024 * 1024;          // D*D
    const size_t MT = 8192 * 1024;          // B*S*D
    u16* wqkv_b = (u16*)alloc(6 * M1 * 2);
    u16* wo_b   = (u16*)alloc(2 * M1 * 2);
    u16* wc1_b  = (u16*)alloc(2 * M1 * 2);
    u16* wc2_b  = (u16*)alloc(2 * M1 * 2);
    u16* wfc_b  = (u16*)alloc(M1 * 2);
    u32* maskw  = (u32*)alloc(8192 * 32 * 4);
    u32* rowfl  = (u32*)alloc(8192 * 4);
    float* sF   = (float*)alloc(MT * 4);
    float* sT   = (float*)alloc(MT * 4);
    u16* t0 = (u16*)alloc(MT * 2);
    u16* qh = (u16*)alloc(MT * 2);
    u16* kh = (u16*)alloc(MT * 2);
    u16* vh = (u16*)alloc(MT * 2);
    u16* xb = (u16*)alloc(MT * 2);

    // weights -> bf16, mask bitpack
    cvt_kernel<<<6 * M1 / 1024, 256, 0, stream>>>(Wqkv, wqkv_b, (int)(6 * M1 / 4));
    cvt_kernel<<<2 * M1 / 1024, 256, 0, stream>>>(Wo,   wo_b,   (int)(2 * M1 / 4));
    cvt_kernel<<<2 * M1 / 1024, 256, 0, stream>>>(Wc1,  wc1_b,  (int)(2 * M1 / 4));
    cvt_kernel<<<2 * M1 / 1024, 256, 0, stream>>>(Wc2,  wc2_b,  (int)(2 * M1 / 4));
    cvt_kernel<<<M1 / 1024, 256, 0, stream>>>(Wfc, wfc_b, (int)(M1 / 4));
    mask_kernel<<<32768, 256, 0, stream>>>(amask, maskw);
    rowflag_kernel<<<32, 256, 0, stream>>>(maskw, rowfl);

    dim3 ggrid(GM / BM, GN / BN);   // (64, 8)
    const int D = 1024;
    for (int i = 0; i < 2; ++i) {
        const float* qsrc = (i == 0) ? q_in : sF;
        // LN1(q) -> t0 (bf16)
        ln_kernel<<<2048, 256, 0, stream>>>(qsrc, ln1g + i * D, ln1b + i * D, t0, nullptr);
        // q projection
        gemm_bt<8><<<ggrid, 256, 0, stream>>>(t0, wqkv_b + (size_t)(i * 3 + 0) * M1,
                                              bqkv + (i * 3 + 0) * D, nullptr, nullptr, qh);
        if (i == 0) cvt_kernel<<<8192, 256, 0, stream>>>(k_in, xb, (int)(MT / 4));
        gemm_bt<8><<<ggrid, 256, 0, stream>>>(xb, wqkv_b + (size_t)(i * 3 + 1) * M1,
                                              bqkv + (i * 3 + 1) * D, nullptr, nullptr, kh);
        if (i == 0) cvt_kernel<<<8192, 256, 0, stream>>>(v_in, xb, (int)(MT / 4));
        gemm_bt<8><<<ggrid, 256, 0, stream>>>(xb, wqkv_b + (size_t)(i * 3 + 2) * M1,
                                              bqkv + (i * 3 + 2) * D, nullptr, nullptr, vh);
        // attention -> t0
        attn_kernel<<<dim3(16, 16, 8), 256, 0, stream>>>(qh, kh, vh, maskw, rowfl, t0);
        // x = relu(attn @ Wo^T + bo); sT = residual + x   (f32)
        const float* resp = (i == 0) ? k_in : sF;
        gemm_bt<1 | 2 | 4><<<ggrid, 256, 0, stream>>>(t0, wo_b + (size_t)i * M1,
                                                      bo + i * D, resp, sT, nullptr);
        // k1 = LN2(sT) -> sF (f32) + xb (bf16)
        ln_kernel<<<2048, 256, 0, stream>>>(sT, ln2g + i * D, ln2b + i * D, xb, sF);
        // h1 = k1 @ Wc1^T + bc1 (bf16) -> qh
        gemm_bt<8><<<ggrid, 256, 0, stream>>>(xb, wc1_b + (size_t)i * M1,
                                              bc1 + i * D, nullptr, nullptr, qh);
        // k2 = k1 + h1 @ Wc2^T + bc2 -> sT (f32) + xb (bf16)
        gemm_bt<2 | 4 | 8><<<ggrid, 256, 0, stream>>>(qh, wc2_b + (size_t)i * M1,
                                                      bc2 + i * D, sF, sT, xb);
        // new state in sT/xb
        float* tmp = sF; sF = sT; sT = tmp;
    }
    // final LN + FC
    ln_kernel<<<2048, 256, 0, stream>>>(sF, lastg, lastb, t0, nullptr);
    gemm_bt<4><<<ggrid, 256, 0, stream>>>(t0, wfc_b, bfc, nullptr, out, nullptr);
}

// Round 3
// 799.390 us; speedup vs baseline: 1.1592x; 1.1592x over previous
//
#include <hip/hip_runtime.h>

typedef __attribute__((ext_vector_type(8))) short s8x;   // 8 x bf16 (raw bits)
typedef __attribute__((ext_vector_type(4))) float f4x;
typedef unsigned short u16;
typedef unsigned int u32;

#define DEV static __device__ __forceinline__

DEV u16 f2b(float f) {
    union { float f; u32 u; } v; v.f = f;
    u32 r = v.u + 0x7FFFu + ((v.u >> 16) & 1u);
    return (u16)(r >> 16);
}

DEV u32 pk2(float lo, float hi) {
    return (u32)f2b(lo) | ((u32)f2b(hi) << 16);
}

DEV void gload16(const void* g, void* lds) {
    __builtin_amdgcn_global_load_lds(
        (const __attribute__((address_space(1))) void*)g,
        (__attribute__((address_space(3))) void*)lds, 16, 0, 0);
}

// ---------------- GEMM: C[M,N] = A[M,K] @ W[N,K]^T + bias, fused epilogue ----------------
// M=8192, N=1024, K=1024 fixed. 128x128 tile, BK=64, 256 threads (4 waves, 2x2), 2-phase dbuf.
#define GM 8192
#define GN 1024
#define GK 1024
#define BM 128
#define BN 128
#define BK 64

template<int FLAGS>
__global__ __launch_bounds__(256) void gemm_bt(
    const u16* __restrict__ A, const u16* __restrict__ W,
    const float* __restrict__ bias, const float* __restrict__ res,
    float* __restrict__ outf, u16* __restrict__ outb)
{
    constexpr bool RELU = (FLAGS & 1) != 0;
    constexpr bool RES  = (FLAGS & 2) != 0;
    constexpr bool WF   = (FLAGS & 4) != 0;
    constexpr bool WB   = (FLAGS & 8) != 0;

    __shared__ __attribute__((aligned(16))) u16 As[2][BM * BK];
    __shared__ __attribute__((aligned(16))) u16 Bs[2][BN * BK];

    const int tid  = threadIdx.x;
    const int lane = tid & 63;
    const int wid  = tid >> 6;
    const int wr = wid >> 1, wc = wid & 1;
    const int bm = blockIdx.x, bn = blockIdx.y;
    const int l15 = lane & 15;
    const int lg  = lane >> 4;

    const u16* Ab = A + (size_t)bm * BM * GK;
    const u16* Wb = W + (size_t)bn * BN * GK;

    const int prow = tid >> 3;          // 0..31, +32 per staging call
    const int pcol = (tid & 7) * 8;     // element col within BK

    f4x acc[4][4];
#pragma unroll
    for (int i = 0; i < 4; ++i)
#pragma unroll
        for (int j = 0; j < 4; ++j) { f4x z = {0.f, 0.f, 0.f, 0.f}; acc[i][j] = z; }

    // prologue: stage kt=0 into buf0
#pragma unroll
    for (int c = 0; c < 4; ++c) {
        int row = c * 32 + prow;
        gload16(Ab + (size_t)row * GK + pcol, &As[0][row * BK + pcol]);
    }
#pragma unroll
    for (int c = 0; c < 4; ++c) {
        int row = c * 32 + prow;
        gload16(Wb + (size_t)row * GK + pcol, &Bs[0][row * BK + pcol]);
    }

    const int nkt = GK / BK;
    int cur = 0;
    for (int kt = 0; kt < nkt; ++kt) {
        __syncthreads();   // buf[cur] staged (vmcnt drained); prev compute on buf[cur^1] done
        if (kt + 1 < nkt) {
            const u16* Ak = Ab + (kt + 1) * BK;
            const u16* Wk = Wb + (kt + 1) * BK;
#pragma unroll
            for (int c = 0; c < 4; ++c) {
                int row = c * 32 + prow;
                gload16(Ak + (size_t)row * GK + pcol, &As[cur ^ 1][row * BK + pcol]);
            }
#pragma unroll
            for (int c = 0; c < 4; ++c) {
                int row = c * 32 + prow;
                gload16(Wk + (size_t)row * GK + pcol, &Bs[cur ^ 1][row * BK + pcol]);
            }
        }
        const u16* Ac = As[cur];
        const u16* Bc = Bs[cur];
#pragma unroll
        for (int kk = 0; kk < 2; ++kk) {
            s8x a[4], b[4];
#pragma unroll
            for (int mi = 0; mi < 4; ++mi)
                a[mi] = *(const s8x*)(Ac + (wr * 64 + mi * 16 + l15) * BK + kk * 32 + lg * 8);
#pragma unroll
            for (int ni = 0; ni < 4; ++ni)
                b[ni] = *(const s8x*)(Bc + (wc * 64 + ni * 16 + l15) * BK + kk * 32 + lg * 8);
#pragma unroll
            for (int mi = 0; mi < 4; ++mi)
#pragma unroll
                for (int ni = 0; ni < 4; ++ni)
                    acc[mi][ni] = __builtin_amdgcn_mfma_f32_16x16x32_bf16(a[mi], b[ni], acc[mi][ni], 0, 0, 0);
        }
        cur ^= 1;
    }

    // epilogue: C/D layout col=lane&15, row=(lane>>4)*4+r
#pragma unroll
    for (int ni = 0; ni < 4; ++ni) {
        int gcol = bn * BN + wc * 64 + ni * 16 + l15;
        float bv = bias[gcol];
#pragma unroll
        for (int mi = 0; mi < 4; ++mi) {
            int grow0 = bm * BM + wr * 64 + mi * 16 + lg * 4;
#pragma unroll
            for (int r = 0; r < 4; ++r) {
                float v = acc[mi][ni][r] + bv;
                if (RELU) v = fmaxf(v, 0.f);
                size_t oidx = (size_t)(grow0 + r) * GN + gcol;
                if (RES) v += res[oidx];
                if (WF) outf[oidx] = v;
                if (WB) outb[oidx] = f2b(v);
            }
        }
    }
}

// ---------------- Attention v2: flash, swapped QK^T, K in LDS (swizzled), 64 q/block ----------------
// Per block: one (b,h,qtile of 64). 4 waves x 16 q-rows. KVBLK=64, 16 tiles.
__global__ __launch_bounds__(256) void attn_kernel(
    const u16* __restrict__ Qm, const u16* __restrict__ Km, const u16* __restrict__ Vm,
    const u32* __restrict__ maskw, const u32* __restrict__ rowfl,
    u16* __restrict__ Om)
{
    const int qt = blockIdx.x;   // 0..15
    const int h  = blockIdx.y;   // 0..15
    const int b  = blockIdx.z;   // 0..7
    const int tid = threadIdx.x, lane = tid & 63, wid = tid >> 6;
    const int l15 = lane & 15, lg = lane >> 4;

    __shared__ __attribute__((aligned(16))) u16 Ks[2][64 * 64];   // swizzled K tile
    __shared__ __attribute__((aligned(16))) u16 Vt[2][64][72];    // V^T (rows = d)
    __shared__ __attribute__((aligned(16))) u16 Ps[4][16][64];    // per-wave P, XOR-swizzled
    __shared__ int anymask;

    const size_t rowbase = (size_t)b * 1024;
    const int hoff = h * 64;

    if (tid == 0) anymask = 0;

    // K staging geometry: dest chunk i gets global chunk i^(row&7)  (rule #21: inverse-swz source)
    const int so0 = tid * 16, so1 = tid * 16 + 4096;        // dest byte offsets
    const int srow0 = so0 >> 7, srow1 = so1 >> 7;           // k-row 0..63
    const int sch0 = ((so0 >> 4) & 7) ^ (srow0 & 7);
    const int sch1 = ((so1 >> 4) & 7) ^ (srow1 & 7);
    const int vswz = (l15 & 7) << 4;                        // Ps byte-XOR key (bits 4..6)

    // prologue: stage tile 0
    {
        const u16* Kt = Km + (rowbase * 1024) + hoff;
        gload16(Kt + (size_t)srow0 * 1024 + sch0 * 8, (char*)Ks[0] + so0);
        gload16(Kt + (size_t)srow1 * 1024 + sch1 * 8, (char*)Ks[0] + so1);
        const u16* Vr = Vm + (rowbase + lane) * 1024 + hoff;
        s8x v0 = *(const s8x*)(Vr + wid * 8);
        s8x v1 = *(const s8x*)(Vr + (wid + 4) * 8);
#pragma unroll
        for (int j = 0; j < 8; ++j) {
            Vt[0][wid * 8 + j][lane]       = (u16)v0[j];
            Vt[0][(wid + 4) * 8 + j][lane] = (u16)v1[j];
        }
    }
    __syncthreads();
    if (tid < 64) {
        if (rowfl[rowbase + qt * 64 + tid]) atomicOr(&anymask, 1);
    }

    // persistent Q fragments (B-operand): lane l15 = q-row wid*16+l15
    const int qrow = qt * 64 + wid * 16 + l15;
    s8x qf[2];
#pragma unroll
    for (int kk = 0; kk < 2; ++kk)
        qf[kk] = *(const s8x*)(Qm + (rowbase + qrow) * 1024 + hoff + kk * 32 + lg * 8);

    f4x o[4];
#pragma unroll
    for (int d = 0; d < 4; ++d) { f4x z = {0.f, 0.f, 0.f, 0.f}; o[d] = z; }
    float mrun = -1e30f, lrun = 0.f;

    __syncthreads();
    const int am = anymask;

    int cur = 0;
    for (int kt = 0; kt < 16; ++kt) {
        const int nxt = cur ^ 1;
        // T14: issue next-tile loads first (K -> LDS direct, V -> regs)
        s8x vv0, vv1;
        if (kt < 15) {
            const u16* Kt = Km + (rowbase + (kt + 1) * 64) * 1024 + hoff;
            gload16(Kt + (size_t)srow0 * 1024 + sch0 * 8, (char*)Ks[nxt] + so0);
            gload16(Kt + (size_t)srow1 * 1024 + sch1 * 8, (char*)Ks[nxt] + so1);
            const u16* Vr = Vm + (rowbase + (kt + 1) * 64 + lane) * 1024 + hoff;
            vv0 = *(const s8x*)(Vr + wid * 8);
            vv1 = *(const s8x*)(Vr + (wid + 4) * 8);
        }

        // swapped QK^T: C[k][q], lane l15 = q, reg (ni,r): k = ni*16 + lg*4 + r
        f4x sc[4];
#pragma unroll
        for (int ni = 0; ni < 4; ++ni) { f4x z = {0.f, 0.f, 0.f, 0.f}; sc[ni] = z; }
#pragma unroll
        for (int kk = 0; kk < 2; ++kk) {
#pragma unroll
            for (int ni = 0; ni < 4; ++ni) {
                int row = ni * 16 + l15;
                int cb  = (kk * 64 + lg * 16) ^ ((row & 7) << 4);
                s8x kf = *(const s8x*)((const char*)Ks[cur] + row * 128 + cb);
                sc[ni] = __builtin_amdgcn_mfma_f32_16x16x32_bf16(kf, qf[kk], sc[ni], 0, 0, 0);
            }
        }
        // scale + clip
#pragma unroll
        for (int ni = 0; ni < 4; ++ni)
#pragma unroll
            for (int r = 0; r < 4; ++r)
                sc[ni][r] = fminf(fmaxf(sc[ni][r] * 0.125f, -30.f), 30.f);
        if (am) {
            int qg = qt * 64 + wid * 16 + l15;
#pragma unroll
            for (int ni = 0; ni < 4; ++ni)
#pragma unroll
                for (int r = 0; r < 4; ++r) {
                    int kcol = kt * 64 + ni * 16 + lg * 4 + r;
                    u32 wb_ = maskw[(rowbase + qg) * 32 + (kcol >> 5)];
                    if (wb_ & (1u << (kcol & 31))) sc[ni][r] = -1e9f;
                }
        }

        // online softmax: in-lane max over 16, then reduce across lg groups (xor 16, 32)
        float mx = fmaxf(fmaxf(fmaxf(sc[0][0], sc[0][1]), fmaxf(sc[0][2], sc[0][3])),
                         fmaxf(fmaxf(sc[1][0], sc[1][1]), fmaxf(sc[1][2], sc[1][3])));
        mx = fmaxf(mx, fmaxf(fmaxf(fmaxf(sc[2][0], sc[2][1]), fmaxf(sc[2][2], sc[2][3])),
                             fmaxf(fmaxf(sc[3][0], sc[3][1]), fmaxf(sc[3][2], sc[3][3]))));
        mx = fmaxf(mx, __shfl_xor(mx, 16));
        mx = fmaxf(mx, __shfl_xor(mx, 32));
        if (!__all(mx <= mrun)) {           // skip-rescale fast path
            float mn = fmaxf(mrun, mx);
            float al = __expf(mrun - mn);
            mrun = mn;
            lrun *= al;
#pragma unroll
            for (int r = 0; r < 4; ++r) {
                float alr = __shfl(al, lg * 4 + r);
#pragma unroll
                for (int d = 0; d < 4; ++d) o[d][r] *= alr;
            }
        }
        float s = 0.f;
#pragma unroll
        for (int ni = 0; ni < 4; ++ni)
#pragma unroll
            for (int r = 0; r < 4; ++r) {
                float p = __expf(sc[ni][r] - mrun);
                sc[ni][r] = p;
                s += p;
            }
        s += __shfl_xor(s, 16);
        s += __shfl_xor(s, 32);
        lrun += s;

        // pack P (bf16 pairs) -> per-wave swizzled LDS, read back as A-frag
#pragma unroll
        for (int ni = 0; ni < 4; ++ni) {
            uint2 w; w.x = pk2(sc[ni][0], sc[ni][1]); w.y = pk2(sc[ni][2], sc[ni][3]);
            *(uint2*)((char*)&Ps[wid][l15][0] + ((ni * 32 + lg * 8) ^ vswz)) = w;
        }
        s8x pa[2];
#pragma unroll
        for (int kk = 0; kk < 2; ++kk)
            pa[kk] = *(const s8x*)((const char*)&Ps[wid][l15][0] + ((kk * 64 + lg * 16) ^ vswz));

        // PV: O[q][d] += P[q][k] V^T[d][k]
#pragma unroll
        for (int d = 0; d < 4; ++d)
#pragma unroll
            for (int kk = 0; kk < 2; ++kk) {
                s8x vf = *(const s8x*)(&Vt[cur][d * 16 + l15][kk * 32 + lg * 8]);
                o[d] = __builtin_amdgcn_mfma_f32_16x16x32_bf16(pa[kk], vf, o[d], 0, 0, 0);
            }

        // late write of next V^T (vv regs have landed under compute)
        if (kt < 15) {
#pragma unroll
            for (int j = 0; j < 8; ++j) {
                Vt[nxt][wid * 8 + j][lane]       = (u16)vv0[j];
                Vt[nxt][(wid + 4) * 8 + j][lane] = (u16)vv1[j];
            }
        }
        __syncthreads();   // drains gload_lds (vmcnt) + Vt writes for next iter
        cur ^= 1;
    }

    // epilogue: O reg (d-tile dt, r): q = wid*16 + lg*4 + r, d = dt*16 + l15
    float rl = 1.f / lrun;
    float rlr[4];
#pragma unroll
    for (int r = 0; r < 4; ++r) rlr[r] = __shfl(rl, lg * 4 + r);
#pragma unroll
    for (int dt = 0; dt < 4; ++dt) {
        int gc = hoff + dt * 16 + l15;
#pragma unroll
        for (int r = 0; r < 4; ++r) {
            int gr = qt * 64 + wid * 16 + lg * 4 + r;
            Om[(rowbase + gr) * 1024 + gc] = f2b(o[dt][r] * rlr[r]);
        }
    }
}

// ---------------- LayerNorm over D=1024, one wave per row, dual bf16/f32 output ----------------
__global__ __launch_bounds__(256) void ln_kernel(
    const float* __restrict__ x, const float* __restrict__ g, const float* __restrict__ bb,
    u16* __restrict__ yb, float* __restrict__ yf)
{
    const int wid = threadIdx.x >> 6, lane = threadIdx.x & 63;
    const size_t row = (size_t)blockIdx.x * 4 + wid;
    const float* xr = x + row * 1024;
    float4 v[4];
    float s = 0.f, s2 = 0.f;
#pragma unroll
    for (int c = 0; c < 4; ++c) {
        v[c] = *(const float4*)(xr + c * 256 + lane * 4);
        s  += v[c].x + v[c].y + v[c].z + v[c].w;
        s2 += v[c].x * v[c].x + v[c].y * v[c].y + v[c].z * v[c].z + v[c].w * v[c].w;
    }
#pragma unroll
    for (int m = 32; m >= 1; m >>= 1) { s += __shfl_xor(s, m); s2 += __shfl_xor(s2, m); }
    float mean = s * (1.f / 1024.f);
    float var  = s2 * (1.f / 1024.f) - mean * mean;
    float rs = rsqrtf(var + 1e-8f);
#pragma unroll
    for (int c = 0; c < 4; ++c) {
        int col = c * 256 + lane * 4;
        float4 gv = *(const float4*)(g + col);
        float4 bv = *(const float4*)(bb + col);
        float y0 = (v[c].x - mean) * rs * gv.x + bv.x;
        float y1 = (v[c].y - mean) * rs * gv.y + bv.y;
        float y2 = (v[c].z - mean) * rs * gv.z + bv.z;
        float y3 = (v[c].w - mean) * rs * gv.w + bv.w;
        if (yb) { ushort4 o4 = make_ushort4(f2b(y0), f2b(y1), f2b(y2), f2b(y3));
                  *(ushort4*)(yb + row * 1024 + col) = o4; }
        if (yf) { float4 o4f = make_float4(y0, y1, y2, y3);
                  *(float4*)(yf + row * 1024 + col) = o4f; }
    }
}

// ---------------- f32 -> bf16 convert ----------------
__global__ __launch_bounds__(256) void cvt_kernel(const float* __restrict__ x, u16* __restrict__ y, int n4)
{
    int i = blockIdx.x * 256 + threadIdx.x;
    if (i < n4) {
        float4 v = *(const float4*)(x + (size_t)i * 4);
        ushort4 o = make_ushort4(f2b(v.x), f2b(v.y), f2b(v.z), f2b(v.w));
        *(ushort4*)(y + (size_t)i * 4) = o;
    }
}

// ---------------- mask bitpack + per-row any-flag ----------------
__global__ __launch_bounds__(256) void mask_kernel(const int* __restrict__ am, u32* __restrict__ mw)
{
    size_t idx = (size_t)blockIdx.x * 256 + threadIdx.x;
    unsigned long long bal = __ballot(am[idx] == 0);
    int lane = threadIdx.x & 63;
    if (lane == 0)  mw[idx >> 5] = (u32)bal;
    if (lane == 32) mw[idx >> 5] = (u32)(bal >> 32);
}

__global__ __launch_bounds__(256) void rowflag_kernel(const u32* __restrict__ mw, u32* __restrict__ rf)
{
    int r = blockIdx.x * 256 + threadIdx.x;   // 8192 rows
    u32 o = 0;
#pragma unroll
    for (int i = 0; i < 32; ++i) o |= mw[r * 32 + i];
    rf[r] = o;
}

// ---------------- host-side orchestration ----------------
extern "C" void kernel_launch(void* const* d_in, const int* in_sizes, int n_in,
                              void* d_out, int out_size, void* d_ws, size_t ws_size,
                              hipStream_t stream)
{
    (void)in_sizes; (void)n_in; (void)out_size; (void)ws_size;

    const float* q_in  = (const float*)d_in[0];
    const float* k_in  = (const float*)d_in[1];
    const float* v_in  = (const float*)d_in[2];
    const int*   amask = (const int*)d_in[3];
    const float* Wqkv  = (const float*)d_in[4];
    const float* bqkv  = (const float*)d_in[5];
    const float* Wo    = (const float*)d_in[6];
    const float* bo    = (const float*)d_in[7];
    const float* ln1g  = (const float*)d_in[8];
    const float* ln1b  = (const float*)d_in[9];
    const float* ln2g  = (const float*)d_in[10];
    const float* ln2b  = (const float*)d_in[11];
    const float* Wc1   = (const float*)d_in[12];
    const float* bc1   = (const float*)d_in[13];
    const float* Wc2   = (const float*)d_in[14];
    const float* bc2   = (const float*)d_in[15];
    const float* lastg = (const float*)d_in[16];
    const float* lastb = (const float*)d_in[17];
    const float* Wfc   = (const float*)d_in[18];
    const float* bfc   = (const float*)d_in[19];
    float* out = (float*)d_out;

    char* base = (char*)d_ws;
    size_t off = 0;
    auto alloc = [&](size_t bytes) -> char* {
        char* p = base + off;
        off = (off + bytes + 255) & ~(size_t)255;
        return p;
    };
    const size_t M1 = 1024 * 1024;          // D*D
    const size_t MT = 8192 * 1024;          // B*S*D
    u16* wqkv_b = (u16*)alloc(6 * M1 * 2);
    u16* wo_b   = (u16*)alloc(2 * M1 * 2);
    u16* wc1_b  = (u16*)alloc(2 * M1 * 2);
    u16* wc2_b  = (u16*)alloc(2 * M1 * 2);
    u16* wfc_b  = (u16*)alloc(M1 * 2);
    u32* maskw  = (u32*)alloc(8192 * 32 * 4);
    u32* rowfl  = (u32*)alloc(8192 * 4);
    float* sF   = (float*)alloc(MT * 4);
    float* sT   = (float*)alloc(MT * 4);
    u16* t0 = (u16*)alloc(MT * 2);
    u16* qh = (u16*)alloc(MT * 2);
    u16* kh = (u16*)alloc(MT * 2);
    u16* vh = (u16*)alloc(MT * 2);
    u16* xb = (u16*)alloc(MT * 2);

    // weights -> bf16, mask bitpack
    cvt_kernel<<<6 * M1 / 1024, 256, 0, stream>>>(Wqkv, wqkv_b, (int)(6 * M1 / 4));
    cvt_kernel<<<2 * M1 / 1024, 256, 0, stream>>>(Wo,   wo_b,   (int)(2 * M1 / 4));
    cvt_kernel<<<2 * M1 / 1024, 256, 0, stream>>>(Wc1,  wc1_b,  (int)(2 * M1 / 4));
    cvt_kernel<<<2 * M1 / 1024, 256, 0, stream>>>(Wc2,  wc2_b,  (int)(2 * M1 / 4));
    cvt_kernel<<<M1 / 1024, 256, 0, stream>>>(Wfc, wfc_b, (int)(M1 / 4));
    mask_kernel<<<32768, 256, 0, stream>>>(amask, maskw);
    rowflag_kernel<<<32, 256, 0, stream>>>(maskw, rowfl);

    dim3 ggrid(GM / BM, GN / BN);   // (64, 8)
    const int D = 1024;
    for (int i = 0; i < 2; ++i) {
        const float* qsrc = (i == 0) ? q_in : sF;
        // LN1(q) -> t0 (bf16)
        ln_kernel<<<2048, 256, 0, stream>>>(qsrc, ln1g + i * D, ln1b + i * D, t0, nullptr);
        // q projection
        gemm_bt<8><<<ggrid, 256, 0, stream>>>(t0, wqkv_b + (size_t)(i * 3 + 0) * M1,
                                              bqkv + (i * 3 + 0) * D, nullptr, nullptr, qh);
        if (i == 0) cvt_kernel<<<8192, 256, 0, stream>>>(k_in, xb, (int)(MT / 4));
        gemm_bt<8><<<ggrid, 256, 0, stream>>>(xb, wqkv_b + (size_t)(i * 3 + 1) * M1,
                                              bqkv + (i * 3 + 1) * D, nullptr, nullptr, kh);
        if (i == 0) cvt_kernel<<<8192, 256, 0, stream>>>(v_in, xb, (int)(MT / 4));
        gemm_bt<8><<<ggrid, 256, 0, stream>>>(xb, wqkv_b + (size_t)(i * 3 + 2) * M1,
                                              bqkv + (i * 3 + 2) * D, nullptr, nullptr, vh);
        // attention -> t0
        attn_kernel<<<dim3(16, 16, 8), 256, 0, stream>>>(qh, kh, vh, maskw, rowfl, t0);
        // x = relu(attn @ Wo^T + bo); sT = residual + x   (f32)
        const float* resp = (i == 0) ? k_in : sF;
        gemm_bt<1 | 2 | 4><<<ggrid, 256, 0, stream>>>(t0, wo_b + (size_t)i * M1,
                                                      bo + i * D, resp, sT, nullptr);
        // k1 = LN2(sT) -> sF (f32) + xb (bf16)
        ln_kernel<<<2048, 256, 0, stream>>>(sT, ln2g + i * D, ln2b + i * D, xb, sF);
        // h1 = k1 @ Wc1^T + bc1 (bf16) -> qh
        gemm_bt<8><<<ggrid, 256, 0, stream>>>(xb, wc1_b + (size_t)i * M1,
                                              bc1 + i * D, nullptr, nullptr, qh);
        // k2 = k1 + h1 @ Wc2^T + bc2 -> sT (f32) + xb (bf16)
        gemm_bt<2 | 4 | 8><<<ggrid, 256, 0, stream>>>(qh, wc2_b + (size_t)i * M1,
                                                      bc2 + i * D, sF, sT, xb);
        // new state in sT/xb
        float* tmp = sF; sF = sT; sT = tmp;
    }
    // final LN + FC
    ln_kernel<<<2048, 256, 0, stream>>>(sF, lastg, lastb, t0, nullptr);
    gemm_bt<4><<<ggrid, 256, 0, stream>>>(t0, wfc_b, bfc, nullptr, out, nullptr);
}

// Round 4
// 732.888 us; speedup vs baseline: 1.2644x; 1.0907x over previous
//
#include <hip/hip_runtime.h>

typedef __attribute__((ext_vector_type(8))) short s8x;   // 8 x bf16 (raw bits)
typedef __attribute__((ext_vector_type(4))) float f4x;
typedef unsigned short u16;
typedef unsigned int u32;

#define DEV static __device__ __forceinline__

DEV u16 f2b(float f) {
    union { float f; u32 u; } v; v.f = f;
    u32 r = v.u + 0x7FFFu + ((v.u >> 16) & 1u);
    return (u16)(r >> 16);
}

DEV u32 pk2(float lo, float hi) {   // v_cvt_pk_bf16_f32: low16=lo, high16=hi
    u32 r;
    asm("v_cvt_pk_bf16_f32 %0, %1, %2" : "=v"(r) : "v"(lo), "v"(hi));
    return r;
}

DEV void gload16(const void* g, void* lds) {
    __builtin_amdgcn_global_load_lds(
        (const __attribute__((address_space(1))) void*)g,
        (__attribute__((address_space(3))) void*)lds, 16, 0, 0);
}

// ---------------- GEMM: C[M,N] = A[M,K] @ W[N,K]^T + bias, fused epilogue ----------------
// K=1024 fixed. 128x128 tile, BK=64, 256 threads (4 waves, 2x2), 2-phase dbuf.
#define GK 1024
#define BM 128
#define BN 128
#define BK 64

template<int FLAGS, int MM, int NN>
__global__ __launch_bounds__(256) void gemm_bt(
    const u16* __restrict__ A, const u16* __restrict__ W,
    const float* __restrict__ bias, const float* __restrict__ res,
    float* __restrict__ outf, u16* __restrict__ outb)
{
    constexpr bool RELU = (FLAGS & 1) != 0;
    constexpr bool RES  = (FLAGS & 2) != 0;
    constexpr bool WF   = (FLAGS & 4) != 0;
    constexpr bool WB   = (FLAGS & 8) != 0;
    constexpr bool RBIA = (FLAGS & 16) != 0;   // bias indexed by row (M) instead of col (N)

    __shared__ __attribute__((aligned(16))) u16 As[2][BM * BK];
    __shared__ __attribute__((aligned(16))) u16 Bs[2][BN * BK];

    const int tid  = threadIdx.x;
    const int lane = tid & 63;
    const int wid  = tid >> 6;
    const int wr = wid >> 1, wc = wid & 1;
    const int bm = blockIdx.x, bn = blockIdx.y;
    const int l15 = lane & 15;
    const int lg  = lane >> 4;

    const u16* Ab = A + (size_t)bm * BM * GK;
    const u16* Wb = W + (size_t)bn * BN * GK;

    const int prow = tid >> 3;          // 0..31, +32 per staging call
    const int pcol = (tid & 7) * 8;     // element col within BK

    f4x acc[4][4];
#pragma unroll
    for (int i = 0; i < 4; ++i)
#pragma unroll
        for (int j = 0; j < 4; ++j) { f4x z = {0.f, 0.f, 0.f, 0.f}; acc[i][j] = z; }

    // prologue: stage kt=0 into buf0
#pragma unroll
    for (int c = 0; c < 4; ++c) {
        int row = c * 32 + prow;
        gload16(Ab + (size_t)row * GK + pcol, &As[0][row * BK + pcol]);
    }
#pragma unroll
    for (int c = 0; c < 4; ++c) {
        int row = c * 32 + prow;
        gload16(Wb + (size_t)row * GK + pcol, &Bs[0][row * BK + pcol]);
    }

    const int nkt = GK / BK;
    int cur = 0;
    for (int kt = 0; kt < nkt; ++kt) {
        __syncthreads();   // buf[cur] staged (vmcnt drained); prev compute on buf[cur^1] done
        if (kt + 1 < nkt) {
            const u16* Ak = Ab + (kt + 1) * BK;
            const u16* Wk = Wb + (kt + 1) * BK;
#pragma unroll
            for (int c = 0; c < 4; ++c) {
                int row = c * 32 + prow;
                gload16(Ak + (size_t)row * GK + pcol, &As[cur ^ 1][row * BK + pcol]);
            }
#pragma unroll
            for (int c = 0; c < 4; ++c) {
                int row = c * 32 + prow;
                gload16(Wk + (size_t)row * GK + pcol, &Bs[cur ^ 1][row * BK + pcol]);
            }
        }
        const u16* Ac = As[cur];
        const u16* Bc = Bs[cur];
#pragma unroll
        for (int kk = 0; kk < 2; ++kk) {
            s8x a[4], b[4];
#pragma unroll
            for (int mi = 0; mi < 4; ++mi)
                a[mi] = *(const s8x*)(Ac + (wr * 64 + mi * 16 + l15) * BK + kk * 32 + lg * 8);
#pragma unroll
            for (int ni = 0; ni < 4; ++ni)
                b[ni] = *(const s8x*)(Bc + (wc * 64 + ni * 16 + l15) * BK + kk * 32 + lg * 8);
#pragma unroll
            for (int mi = 0; mi < 4; ++mi)
#pragma unroll
                for (int ni = 0; ni < 4; ++ni)
                    acc[mi][ni] = __builtin_amdgcn_mfma_f32_16x16x32_bf16(a[mi], b[ni], acc[mi][ni], 0, 0, 0);
        }
        cur ^= 1;
    }

    // epilogue: C/D layout col=lane&15, row=(lane>>4)*4+r
#pragma unroll
    for (int ni = 0; ni < 4; ++ni) {
        int gcol = bn * BN + wc * 64 + ni * 16 + l15;
        float bvc = RBIA ? 0.f : bias[gcol];
#pragma unroll
        for (int mi = 0; mi < 4; ++mi) {
            int grow0 = bm * BM + wr * 64 + mi * 16 + lg * 4;
#pragma unroll
            for (int r = 0; r < 4; ++r) {
                float bv = RBIA ? bias[grow0 + r] : bvc;
                float v = acc[mi][ni][r] + bv;
                if (RELU) v = fmaxf(v, 0.f);
                size_t oidx = (size_t)(grow0 + r) * NN + gcol;
                if (RES) v += res[oidx];
                if (WF) outf[oidx] = v;
                if (WB) outb[oidx] = f2b(v);
            }
        }
    }
}

// ---------------- Attention v3: QBLK=128, 8 waves, K and V^T both swizzled-LDS staged ----------------
// grid = (bh=128, qt=8). Blocks sharing a (b,h) K/V panel differ only in blockIdx.y ->
// linear ids differ by 128 (== 0 mod 8) -> same XCD -> panel L2-resident.
// Vt global layout: [1024 d_global][8192 s_global] (produced by swapped V-projection GEMM).
__global__ __launch_bounds__(512) void attn_kernel(
    const u16* __restrict__ Qm, const u16* __restrict__ Km, const u16* __restrict__ Vt,
    const u32* __restrict__ maskw, const u32* __restrict__ rowfl,
    u16* __restrict__ Om)
{
    const int bh = blockIdx.x;
    const int b  = bh >> 4;
    const int h  = bh & 15;
    const int qt = blockIdx.y;   // 0..7, 128 q-rows each
    const int tid = threadIdx.x, lane = tid & 63, wid = tid >> 6;
    const int l15 = lane & 15, lg = lane >> 4;

    __shared__ __attribute__((aligned(16))) u16 Ks[2][64 * 64];   // swizzled K tile [krow][d]
    __shared__ __attribute__((aligned(16))) u16 Vs[2][64 * 64];   // swizzled V^T tile [drow][k]
    __shared__ __attribute__((aligned(16))) u16 Ps[8][16][64];    // per-wave P, XOR-swizzled
    __shared__ int anymask;

    const size_t rowbase = (size_t)b * 1024;
    const int hoff = h * 64;

    if (tid == 0) anymask = 0;

    // staging geometry: 512 threads x 16B = one 8KB tile per buffer.
    // dest chunk cd at row gets global chunk cd ^ (row&7)  (rule #21)
    const int so   = tid * 16;
    const int srow = so >> 7;                       // 0..63
    const int sch  = ((so >> 4) & 7) ^ (srow & 7);
    const int vswz = (l15 & 7) << 4;                // Ps byte-XOR key

    const u16* Kbase = Km + rowbase * 1024 + hoff;          // [s][1024]
    const u16* Vbase = Vt + (size_t)(hoff + srow) * 8192 + b * 1024;  // row = d

    // prologue: stage tile 0
    gload16(Kbase + (size_t)srow * 1024 + sch * 8, (char*)Ks[0] + so);
    gload16(Vbase + sch * 8,                       (char*)Vs[0] + so);

    __syncthreads();
    if (tid < 128) {
        if (rowfl[rowbase + qt * 128 + tid]) atomicOr(&anymask, 1);
    }

    // persistent Q fragments (B-operand): lane l15 = q-row wid*16+l15
    const int qrow = qt * 128 + wid * 16 + l15;
    s8x qf[2];
#pragma unroll
    for (int kk = 0; kk < 2; ++kk)
        qf[kk] = *(const s8x*)(Qm + (rowbase + qrow) * 1024 + hoff + kk * 32 + lg * 8);

    f4x o[4];
#pragma unroll
    for (int d = 0; d < 4; ++d) { f4x z = {0.f, 0.f, 0.f, 0.f}; o[d] = z; }
    float mrun = -1e30f, lrun = 0.f;

    __syncthreads();
    const int am = anymask;

    int cur = 0;
    for (int kt = 0; kt < 16; ++kt) {
        // issue next-tile staging first (T14): latency hides under this tile's compute
        if (kt < 15) {
            gload16(Kbase + (size_t)(kt + 1) * 64 * 1024 + (size_t)srow * 1024 + sch * 8,
                    (char*)Ks[cur ^ 1] + so);
            gload16(Vbase + (kt + 1) * 64 + sch * 8, (char*)Vs[cur ^ 1] + so);
        }

        // swapped QK^T: C[k][q], lane l15 = q, reg (ni,r): k = ni*16 + lg*4 + r
        f4x sc[4];
#pragma unroll
        for (int ni = 0; ni < 4; ++ni) { f4x z = {0.f, 0.f, 0.f, 0.f}; sc[ni] = z; }
        __builtin_amdgcn_s_setprio(1);
#pragma unroll
        for (int kk = 0; kk < 2; ++kk) {
#pragma unroll
            for (int ni = 0; ni < 4; ++ni) {
                int row = ni * 16 + l15;
                int cb  = (kk * 64 + lg * 16) ^ ((row & 7) << 4);
                s8x kf = *(const s8x*)((const char*)Ks[cur] + row * 128 + cb);
                sc[ni] = __builtin_amdgcn_mfma_f32_16x16x32_bf16(kf, qf[kk], sc[ni], 0, 0, 0);
            }
        }
        __builtin_amdgcn_s_setprio(0);

        // scale + clip
#pragma unroll
        for (int ni = 0; ni < 4; ++ni)
#pragma unroll
            for (int r = 0; r < 4; ++r)
                sc[ni][r] = fminf(fmaxf(sc[ni][r] * 0.125f, -30.f), 30.f);
        if (am) {
            int qg = qt * 128 + wid * 16 + l15;
#pragma unroll
            for (int ni = 0; ni < 4; ++ni)
#pragma unroll
                for (int r = 0; r < 4; ++r) {
                    int kcol = kt * 64 + ni * 16 + lg * 4 + r;
                    u32 wb_ = maskw[(rowbase + qg) * 32 + (kcol >> 5)];
                    if (wb_ & (1u << (kcol & 31))) sc[ni][r] = -1e9f;
                }
        }

        // online softmax: in-lane max over 16 k, reduce across lg groups (xor 16, 32)
        float mx = fmaxf(fmaxf(fmaxf(sc[0][0], sc[0][1]), fmaxf(sc[0][2], sc[0][3])),
                         fmaxf(fmaxf(sc[1][0], sc[1][1]), fmaxf(sc[1][2], sc[1][3])));
        mx = fmaxf(mx, fmaxf(fmaxf(fmaxf(sc[2][0], sc[2][1]), fmaxf(sc[2][2], sc[2][3])),
                             fmaxf(fmaxf(sc[3][0], sc[3][1]), fmaxf(sc[3][2], sc[3][3]))));
        mx = fmaxf(mx, __shfl_xor(mx, 16));
        mx = fmaxf(mx, __shfl_xor(mx, 32));
        if (!__all(mx <= mrun)) {           // skip-rescale fast path
            float mn = fmaxf(mrun, mx);
            float al = __expf(mrun - mn);
            mrun = mn;
            lrun *= al;
#pragma unroll
            for (int r = 0; r < 4; ++r) {
                float alr = __shfl(al, lg * 4 + r);
#pragma unroll
                for (int d = 0; d < 4; ++d) o[d][r] *= alr;
            }
        }
        float s = 0.f;
#pragma unroll
        for (int ni = 0; ni < 4; ++ni)
#pragma unroll
            for (int r = 0; r < 4; ++r) {
                float p = __expf(sc[ni][r] - mrun);
                sc[ni][r] = p;
                s += p;
            }
        s += __shfl_xor(s, 16);
        s += __shfl_xor(s, 32);
        lrun += s;

        // pack P (v_cvt_pk_bf16_f32) -> per-wave swizzled LDS, read back as A-frag
#pragma unroll
        for (int ni = 0; ni < 4; ++ni) {
            uint2 w; w.x = pk2(sc[ni][0], sc[ni][1]); w.y = pk2(sc[ni][2], sc[ni][3]);
            *(uint2*)((char*)&Ps[wid][l15][0] + ((ni * 32 + lg * 8) ^ vswz)) = w;
        }
        s8x pa[2];
#pragma unroll
        for (int kk = 0; kk < 2; ++kk)
            pa[kk] = *(const s8x*)((const char*)&Ps[wid][l15][0] + ((kk * 64 + lg * 16) ^ vswz));

        // PV: O[q][d] += P[q][k] * V^T[d][k]  (B-frag from swizzled Vs, same pattern as K)
        __builtin_amdgcn_s_setprio(1);
#pragma unroll
        for (int dt = 0; dt < 4; ++dt)
#pragma unroll
            for (int kk = 0; kk < 2; ++kk) {
                int row = dt * 16 + l15;
                int cb  = (kk * 64 + lg * 16) ^ ((row & 7) << 4);
                s8x vf = *(const s8x*)((const char*)Vs[cur] + row * 128 + cb);
                o[dt] = __builtin_amdgcn_mfma_f32_16x16x32_bf16(pa[kk], vf, o[dt], 0, 0, 0);
            }
        __builtin_amdgcn_s_setprio(0);

        __syncthreads();   // drains gload_lds (vmcnt) for next tile; guards cur^1 overwrite
        cur ^= 1;
    }

    // epilogue: O reg (dt, r): q = wid*16 + lg*4 + r (within qtile), d = dt*16 + l15
    float rl = 1.f / lrun;
    float rlr[4];
#pragma unroll
    for (int r = 0; r < 4; ++r) rlr[r] = __shfl(rl, lg * 4 + r);
#pragma unroll
    for (int dt = 0; dt < 4; ++dt) {
        int gc = hoff + dt * 16 + l15;
#pragma unroll
        for (int r = 0; r < 4; ++r) {
            int gr = qt * 128 + wid * 16 + lg * 4 + r;
            Om[(rowbase + gr) * 1024 + gc] = f2b(o[dt][r] * rlr[r]);
        }
    }
}

// ---------------- LayerNorm over D=1024, one wave per row, dual bf16/f32 output ----------------
__global__ __launch_bounds__(256) void ln_kernel(
    const float* __restrict__ x, const float* __restrict__ g, const float* __restrict__ bb,
    u16* __restrict__ yb, float* __restrict__ yf)
{
    const int wid = threadIdx.x >> 6, lane = threadIdx.x & 63;
    const size_t row = (size_t)blockIdx.x * 4 + wid;
    const float* xr = x + row * 1024;
    float4 v[4];
    float s = 0.f, s2 = 0.f;
#pragma unroll
    for (int c = 0; c < 4; ++c) {
        v[c] = *(const float4*)(xr + c * 256 + lane * 4);
        s  += v[c].x + v[c].y + v[c].z + v[c].w;
        s2 += v[c].x * v[c].x + v[c].y * v[c].y + v[c].z * v[c].z + v[c].w * v[c].w;
    }
#pragma unroll
    for (int m = 32; m >= 1; m >>= 1) { s += __shfl_xor(s, m); s2 += __shfl_xor(s2, m); }
    float mean = s * (1.f / 1024.f);
    float var  = s2 * (1.f / 1024.f) - mean * mean;
    float rs = rsqrtf(var + 1e-8f);
#pragma unroll
    for (int c = 0; c < 4; ++c) {
        int col = c * 256 + lane * 4;
        float4 gv = *(const float4*)(g + col);
        float4 bv = *(const float4*)(bb + col);
        float y0 = (v[c].x - mean) * rs * gv.x + bv.x;
        float y1 = (v[c].y - mean) * rs * gv.y + bv.y;
        float y2 = (v[c].z - mean) * rs * gv.z + bv.z;
        float y3 = (v[c].w - mean) * rs * gv.w + bv.w;
        if (yb) { ushort4 o4 = make_ushort4(f2b(y0), f2b(y1), f2b(y2), f2b(y3));
                  *(ushort4*)(yb + row * 1024 + col) = o4; }
        if (yf) { float4 o4f = make_float4(y0, y1, y2, y3);
                  *(float4*)(yf + row * 1024 + col) = o4f; }
    }
}

// ---------------- f32 -> bf16 convert ----------------
__global__ __launch_bounds__(256) void cvt_kernel(const float* __restrict__ x, u16* __restrict__ y, int n4)
{
    int i = blockIdx.x * 256 + threadIdx.x;
    if (i < n4) {
        float4 v = *(const float4*)(x + (size_t)i * 4);
        ushort4 o = make_ushort4(f2b(v.x), f2b(v.y), f2b(v.z), f2b(v.w));
        *(ushort4*)(y + (size_t)i * 4) = o;
    }
}

// ---------------- mask bitpack + per-row any-flag ----------------
__global__ __launch_bounds__(256) void mask_kernel(const int* __restrict__ am, u32* __restrict__ mw)
{
    size_t idx = (size_t)blockIdx.x * 256 + threadIdx.x;
    unsigned long long bal = __ballot(am[idx] == 0);
    int lane = threadIdx.x & 63;
    if (lane == 0)  mw[idx >> 5] = (u32)bal;
    if (lane == 32) mw[idx >> 5] = (u32)(bal >> 32);
}

__global__ __launch_bounds__(256) void rowflag_kernel(const u32* __restrict__ mw, u32* __restrict__ rf)
{
    int r = blockIdx.x * 256 + threadIdx.x;   // 8192 rows
    u32 o = 0;
#pragma unroll
    for (int i = 0; i < 32; ++i) o |= mw[r * 32 + i];
    rf[r] = o;
}

// ---------------- host-side orchestration ----------------
extern "C" void kernel_launch(void* const* d_in, const int* in_sizes, int n_in,
                              void* d_out, int out_size, void* d_ws, size_t ws_size,
                              hipStream_t stream)
{
    (void)in_sizes; (void)n_in; (void)out_size; (void)ws_size;

    const float* q_in  = (const float*)d_in[0];
    const float* k_in  = (const float*)d_in[1];
    const float* v_in  = (const float*)d_in[2];
    const int*   amask = (const int*)d_in[3];
    const float* Wqkv  = (const float*)d_in[4];
    const float* bqkv  = (const float*)d_in[5];
    const float* Wo    = (const float*)d_in[6];
    const float* bo    = (const float*)d_in[7];
    const float* ln1g  = (const float*)d_in[8];
    const float* ln1b  = (const float*)d_in[9];
    const float* ln2g  = (const float*)d_in[10];
    const float* ln2b  = (const float*)d_in[11];
    const float* Wc1   = (const float*)d_in[12];
    const float* bc1   = (const float*)d_in[13];
    const float* Wc2   = (const float*)d_in[14];
    const float* bc2   = (const float*)d_in[15];
    const float* lastg = (const float*)d_in[16];
    const float* lastb = (const float*)d_in[17];
    const float* Wfc   = (const float*)d_in[18];
    const float* bfc   = (const float*)d_in[19];
    float* out = (float*)d_out;

    char* base = (char*)d_ws;
    size_t off = 0;
    auto alloc = [&](size_t bytes) -> char* {
        char* p = base + off;
        off = (off + bytes + 255) & ~(size_t)255;
        return p;
    };
    const size_t M1 = 1024 * 1024;          // D*D
    const size_t MT = 8192 * 1024;          // B*S*D
    u16* wqkv_b = (u16*)alloc(6 * M1 * 2);
    u16* wo_b   = (u16*)alloc(2 * M1 * 2);
    u16* wc1_b  = (u16*)alloc(2 * M1 * 2);
    u16* wc2_b  = (u16*)alloc(2 * M1 * 2);
    u16* wfc_b  = (u16*)alloc(M1 * 2);
    u32* maskw  = (u32*)alloc(8192 * 32 * 4);
    u32* rowfl  = (u32*)alloc(8192 * 4);
    float* sF   = (float*)alloc(MT * 4);
    float* sT   = (float*)alloc(MT * 4);
    u16* t0 = (u16*)alloc(MT * 2);
    u16* qh = (u16*)alloc(MT * 2);
    u16* kh = (u16*)alloc(MT * 2);
    u16* vt = (u16*)alloc(MT * 2);          // V^T: [1024 d_global][8192 s_global]
    u16* xb = (u16*)alloc(MT * 2);

    // weights -> bf16, mask bitpack
    cvt_kernel<<<6 * M1 / 1024, 256, 0, stream>>>(Wqkv, wqkv_b, (int)(6 * M1 / 4));
    cvt_kernel<<<2 * M1 / 1024, 256, 0, stream>>>(Wo,   wo_b,   (int)(2 * M1 / 4));
    cvt_kernel<<<2 * M1 / 1024, 256, 0, stream>>>(Wc1,  wc1_b,  (int)(2 * M1 / 4));
    cvt_kernel<<<2 * M1 / 1024, 256, 0, stream>>>(Wc2,  wc2_b,  (int)(2 * M1 / 4));
    cvt_kernel<<<M1 / 1024, 256, 0, stream>>>(Wfc, wfc_b, (int)(M1 / 4));
    mask_kernel<<<32768, 256, 0, stream>>>(amask, maskw);
    rowflag_kernel<<<32, 256, 0, stream>>>(maskw, rowfl);

    dim3 ggrid(8192 / BM, 1024 / BN);   // (64, 8) standard shape
    dim3 vgrid(1024 / BM, 8192 / BN);   // (8, 64) swapped V-projection
    const int D = 1024;
    for (int i = 0; i < 2; ++i) {
        const float* qsrc = (i == 0) ? q_in : sF;
        // LN1(q) -> t0 (bf16)
        ln_kernel<<<2048, 256, 0, stream>>>(qsrc, ln1g + i * D, ln1b + i * D, t0, nullptr);
        // q projection
        gemm_bt<8, 8192, 1024><<<ggrid, 256, 0, stream>>>(t0, wqkv_b + (size_t)(i * 3 + 0) * M1,
                                              bqkv + (i * 3 + 0) * D, nullptr, nullptr, qh);
        if (i == 0) cvt_kernel<<<8192, 256, 0, stream>>>(k_in, xb, (int)(MT / 4));
        gemm_bt<8, 8192, 1024><<<ggrid, 256, 0, stream>>>(xb, wqkv_b + (size_t)(i * 3 + 1) * M1,
                                              bqkv + (i * 3 + 1) * D, nullptr, nullptr, kh);
        if (i == 0) cvt_kernel<<<8192, 256, 0, stream>>>(v_in, xb, (int)(MT / 4));
        // V projection, swapped: vt[d][s] = W_v · X^T  (row-bias)
        gemm_bt<8 | 16, 1024, 8192><<<vgrid, 256, 0, stream>>>(wqkv_b + (size_t)(i * 3 + 2) * M1, xb,
                                              bqkv + (i * 3 + 2) * D, nullptr, nullptr, vt);
        // attention -> t0
        attn_kernel<<<dim3(128, 8), 512, 0, stream>>>(qh, kh, vt, maskw, rowfl, t0);
        // x = relu(attn @ Wo^T + bo); sT = residual + x   (f32)
        const float* resp = (i == 0) ? k_in : sF;
        gemm_bt<1 | 2 | 4, 8192, 1024><<<ggrid, 256, 0, stream>>>(t0, wo_b + (size_t)i * M1,
                                                      bo + i * D, resp, sT, nullptr);
        // k1 = LN2(sT) -> sF (f32) + xb (bf16)
        ln_kernel<<<2048, 256, 0, stream>>>(sT, ln2g + i * D, ln2b + i * D, xb, sF);
        // h1 = k1 @ Wc1^T + bc1 (bf16) -> qh
        gemm_bt<8, 8192, 1024><<<ggrid, 256, 0, stream>>>(xb, wc1_b + (size_t)i * M1,
                                              bc1 + i * D, nullptr, nullptr, qh);
        // k2 = k1 + h1 @ Wc2^T + bc2 -> sT (f32) + xb (bf16)
        gemm_bt<2 | 4 | 8, 8192, 1024><<<ggrid, 256, 0, stream>>>(qh, wc2_b + (size_t)i * M1,
                                                      bc2 + i * D, sF, sT, xb);
        // new state in sT/xb
        float* tmp = sF; sF = sT; sT = tmp;
    }
    // final LN + FC
    ln_kernel<<<2048, 256, 0, stream>>>(sF, lastg, lastb, t0, nullptr);
    gemm_bt<4, 8192, 1024><<<ggrid, 256, 0, stream>>>(t0, wfc_b, bfc, nullptr, out, nullptr);
}

// Round 5
// 695.243 us; speedup vs baseline: 1.3329x; 1.0541x over previous
//
#include <hip/hip_runtime.h>

typedef __attribute__((ext_vector_type(8))) short s8x;   // 8 x bf16 (raw bits)
typedef __attribute__((ext_vector_type(4))) float f4x;
typedef unsigned short u16;
typedef unsigned int u32;

#define DEV static __device__ __forceinline__

DEV u16 f2b(float f) {
    union { float f; u32 u; } v; v.f = f;
    u32 r = v.u + 0x7FFFu + ((v.u >> 16) & 1u);
    return (u16)(r >> 16);
}

DEV u32 pk2(float lo, float hi) {   // v_cvt_pk_bf16_f32: low16=lo, high16=hi
    u32 r;
    asm("v_cvt_pk_bf16_f32 %0, %1, %2" : "=v"(r) : "v"(lo), "v"(hi));
    return r;
}

DEV void gload16(const void* g, void* lds) {
    __builtin_amdgcn_global_load_lds(
        (const __attribute__((address_space(1))) void*)g,
        (__attribute__((address_space(3))) void*)lds, 16, 0, 0);
}

// ---------------- GEMM: C[M,N] = A[M,K] @ W[N,K]^T + bias, fused epilogue ----------------
// K=1024 fixed. 128x128 tile, BK=64, 256 threads (4 waves, 2x2), 2-phase dbuf.
#define GK 1024
#define BM 128
#define BN 128
#define BK 64

template<int FLAGS, int NN>
__global__ __launch_bounds__(256) void gemm_bt(
    const u16* __restrict__ A, const u16* __restrict__ W,
    const float* __restrict__ bias, const float* __restrict__ res,
    float* __restrict__ outf, u16* __restrict__ outb)
{
    constexpr bool RELU = (FLAGS & 1) != 0;
    constexpr bool RES  = (FLAGS & 2) != 0;
    constexpr bool WF   = (FLAGS & 4) != 0;
    constexpr bool WB   = (FLAGS & 8) != 0;
    constexpr bool RBIA = (FLAGS & 16) != 0;   // bias indexed by row (M) instead of col (N)

    __shared__ __attribute__((aligned(16))) u16 As[2][BM * BK];
    __shared__ __attribute__((aligned(16))) u16 Bs[2][BN * BK];

    const int tid  = threadIdx.x;
    const int lane = tid & 63;
    const int wid  = tid >> 6;
    const int wr = wid >> 1, wc = wid & 1;
    const int bm = blockIdx.x, bn = blockIdx.y;
    const int l15 = lane & 15;
    const int lg  = lane >> 4;

    const u16* Ab = A + (size_t)bm * BM * GK;
    const u16* Wb = W + (size_t)bn * BN * GK;

    const int prow = tid >> 3;
    const int pcol = (tid & 7) * 8;

    f4x acc[4][4];
#pragma unroll
    for (int i = 0; i < 4; ++i)
#pragma unroll
        for (int j = 0; j < 4; ++j) { f4x z = {0.f, 0.f, 0.f, 0.f}; acc[i][j] = z; }

#pragma unroll
    for (int c = 0; c < 4; ++c) {
        int row = c * 32 + prow;
        gload16(Ab + (size_t)row * GK + pcol, &As[0][row * BK + pcol]);
    }
#pragma unroll
    for (int c = 0; c < 4; ++c) {
        int row = c * 32 + prow;
        gload16(Wb + (size_t)row * GK + pcol, &Bs[0][row * BK + pcol]);
    }

    const int nkt = GK / BK;
    int cur = 0;
    for (int kt = 0; kt < nkt; ++kt) {
        __syncthreads();
        if (kt + 1 < nkt) {
            const u16* Ak = Ab + (kt + 1) * BK;
            const u16* Wk = Wb + (kt + 1) * BK;
#pragma unroll
            for (int c = 0; c < 4; ++c) {
                int row = c * 32 + prow;
                gload16(Ak + (size_t)row * GK + pcol, &As[cur ^ 1][row * BK + pcol]);
            }
#pragma unroll
            for (int c = 0; c < 4; ++c) {
                int row = c * 32 + prow;
                gload16(Wk + (size_t)row * GK + pcol, &Bs[cur ^ 1][row * BK + pcol]);
            }
        }
        const u16* Ac = As[cur];
        const u16* Bc = Bs[cur];
#pragma unroll
        for (int kk = 0; kk < 2; ++kk) {
            s8x a[4], b[4];
#pragma unroll
            for (int mi = 0; mi < 4; ++mi)
                a[mi] = *(const s8x*)(Ac + (wr * 64 + mi * 16 + l15) * BK + kk * 32 + lg * 8);
#pragma unroll
            for (int ni = 0; ni < 4; ++ni)
                b[ni] = *(const s8x*)(Bc + (wc * 64 + ni * 16 + l15) * BK + kk * 32 + lg * 8);
#pragma unroll
            for (int mi = 0; mi < 4; ++mi)
#pragma unroll
                for (int ni = 0; ni < 4; ++ni)
                    acc[mi][ni] = __builtin_amdgcn_mfma_f32_16x16x32_bf16(a[mi], b[ni], acc[mi][ni], 0, 0, 0);
        }
        cur ^= 1;
    }

#pragma unroll
    for (int ni = 0; ni < 4; ++ni) {
        int gcol = bn * BN + wc * 64 + ni * 16 + l15;
        float bvc = RBIA ? 0.f : bias[gcol];
#pragma unroll
        for (int mi = 0; mi < 4; ++mi) {
            int grow0 = bm * BM + wr * 64 + mi * 16 + lg * 4;
#pragma unroll
            for (int r = 0; r < 4; ++r) {
                float bv = RBIA ? bias[grow0 + r] : bvc;
                float v = acc[mi][ni][r] + bv;
                if (RELU) v = fmaxf(v, 0.f);
                size_t oidx = (size_t)(grow0 + r) * NN + gcol;
                if (RES) v += res[oidx];
                if (WF) outf[oidx] = v;
                if (WB) outb[oidx] = f2b(v);
            }
        }
    }
}

// ---- z-batched variant: two independent (A,W,bias,out,scale) sets, bf16 out only ----
// epilogue: out = f2b((acc + bias) * scl)
__global__ __launch_bounds__(256) void gemm_z2(
    const u16* __restrict__ A0, const u16* __restrict__ W0, const float* __restrict__ b0,
    u16* __restrict__ o0, float s0,
    const u16* __restrict__ A1, const u16* __restrict__ W1, const float* __restrict__ b1,
    u16* __restrict__ o1, float s1)
{
    const int z = blockIdx.z;
    const u16* A = z ? A1 : A0;
    const u16* W = z ? W1 : W0;
    const float* bias = z ? b1 : b0;
    u16* outb = z ? o1 : o0;
    const float scl = z ? s1 : s0;

    __shared__ __attribute__((aligned(16))) u16 As[2][BM * BK];
    __shared__ __attribute__((aligned(16))) u16 Bs[2][BN * BK];

    const int tid  = threadIdx.x;
    const int lane = tid & 63;
    const int wid  = tid >> 6;
    const int wr = wid >> 1, wc = wid & 1;
    const int bm = blockIdx.x, bn = blockIdx.y;
    const int l15 = lane & 15;
    const int lg  = lane >> 4;

    const u16* Ab = A + (size_t)bm * BM * GK;
    const u16* Wb = W + (size_t)bn * BN * GK;

    const int prow = tid >> 3;
    const int pcol = (tid & 7) * 8;

    f4x acc[4][4];
#pragma unroll
    for (int i = 0; i < 4; ++i)
#pragma unroll
        for (int j = 0; j < 4; ++j) { f4x z_ = {0.f, 0.f, 0.f, 0.f}; acc[i][j] = z_; }

#pragma unroll
    for (int c = 0; c < 4; ++c) {
        int row = c * 32 + prow;
        gload16(Ab + (size_t)row * GK + pcol, &As[0][row * BK + pcol]);
    }
#pragma unroll
    for (int c = 0; c < 4; ++c) {
        int row = c * 32 + prow;
        gload16(Wb + (size_t)row * GK + pcol, &Bs[0][row * BK + pcol]);
    }

    const int nkt = GK / BK;
    int cur = 0;
    for (int kt = 0; kt < nkt; ++kt) {
        __syncthreads();
        if (kt + 1 < nkt) {
            const u16* Ak = Ab + (kt + 1) * BK;
            const u16* Wk = Wb + (kt + 1) * BK;
#pragma unroll
            for (int c = 0; c < 4; ++c) {
                int row = c * 32 + prow;
                gload16(Ak + (size_t)row * GK + pcol, &As[cur ^ 1][row * BK + pcol]);
            }
#pragma unroll
            for (int c = 0; c < 4; ++c) {
                int row = c * 32 + prow;
                gload16(Wk + (size_t)row * GK + pcol, &Bs[cur ^ 1][row * BK + pcol]);
            }
        }
        const u16* Ac = As[cur];
        const u16* Bc = Bs[cur];
#pragma unroll
        for (int kk = 0; kk < 2; ++kk) {
            s8x a[4], b[4];
#pragma unroll
            for (int mi = 0; mi < 4; ++mi)
                a[mi] = *(const s8x*)(Ac + (wr * 64 + mi * 16 + l15) * BK + kk * 32 + lg * 8);
#pragma unroll
            for (int ni = 0; ni < 4; ++ni)
                b[ni] = *(const s8x*)(Bc + (wc * 64 + ni * 16 + l15) * BK + kk * 32 + lg * 8);
#pragma unroll
            for (int mi = 0; mi < 4; ++mi)
#pragma unroll
                for (int ni = 0; ni < 4; ++ni)
                    acc[mi][ni] = __builtin_amdgcn_mfma_f32_16x16x32_bf16(a[mi], b[ni], acc[mi][ni], 0, 0, 0);
        }
        cur ^= 1;
    }

#pragma unroll
    for (int ni = 0; ni < 4; ++ni) {
        int gcol = bn * BN + wc * 64 + ni * 16 + l15;
        float bvc = bias[gcol];
#pragma unroll
        for (int mi = 0; mi < 4; ++mi) {
            int grow0 = bm * BM + wr * 64 + mi * 16 + lg * 4;
#pragma unroll
            for (int r = 0; r < 4; ++r) {
                float v = (acc[mi][ni][r] + bvc) * scl;
                outb[(size_t)(grow0 + r) * 1024 + gcol] = f2b(v);
            }
        }
    }
}

// ---------------- Attention v4: QBLK=128, 8 waves, prescaled Q, defer-max THR=8 ----------------
__global__ __launch_bounds__(512) void attn_kernel(
    const u16* __restrict__ Qm, const u16* __restrict__ Km, const u16* __restrict__ Vt,
    const u32* __restrict__ maskw, const u32* __restrict__ rowfl,
    u16* __restrict__ Om)
{
    const int bh = blockIdx.x;
    const int b  = bh >> 4;
    const int h  = bh & 15;
    const int qt = blockIdx.y;   // 0..7, 128 q-rows each
    const int tid = threadIdx.x, lane = tid & 63, wid = tid >> 6;
    const int l15 = lane & 15, lg = lane >> 4;

    __shared__ __attribute__((aligned(16))) u16 Ks[2][64 * 64];
    __shared__ __attribute__((aligned(16))) u16 Vs[2][64 * 64];
    __shared__ __attribute__((aligned(16))) u16 Ps[8][16][64];
    __shared__ int anymask;

    const size_t rowbase = (size_t)b * 1024;
    const int hoff = h * 64;

    if (tid == 0) anymask = 0;

    const int so   = tid * 16;
    const int srow = so >> 7;
    const int sch  = ((so >> 4) & 7) ^ (srow & 7);
    const int vswz = (l15 & 7) << 4;

    const u16* Kbase = Km + rowbase * 1024 + hoff;
    const u16* Vbase = Vt + (size_t)(hoff + srow) * 8192 + b * 1024;

    gload16(Kbase + (size_t)srow * 1024 + sch * 8, (char*)Ks[0] + so);
    gload16(Vbase + sch * 8,                       (char*)Vs[0] + so);

    __syncthreads();
    if (tid < 128) {
        if (rowfl[rowbase + qt * 128 + tid]) atomicOr(&anymask, 1);
    }

    const int qrow = qt * 128 + wid * 16 + l15;
    s8x qf[2];
#pragma unroll
    for (int kk = 0; kk < 2; ++kk)
        qf[kk] = *(const s8x*)(Qm + (rowbase + qrow) * 1024 + hoff + kk * 32 + lg * 8);

    f4x o[4];
#pragma unroll
    for (int d = 0; d < 4; ++d) { f4x z = {0.f, 0.f, 0.f, 0.f}; o[d] = z; }
    float mrun = -1e30f, lrun = 0.f;

    __syncthreads();
    const int am = anymask;

    int cur = 0;
    for (int kt = 0; kt < 16; ++kt) {
        if (kt < 15) {
            gload16(Kbase + (size_t)(kt + 1) * 64 * 1024 + (size_t)srow * 1024 + sch * 8,
                    (char*)Ks[cur ^ 1] + so);
            gload16(Vbase + (kt + 1) * 64 + sch * 8, (char*)Vs[cur ^ 1] + so);
        }

        // swapped QK^T: C[k][q]; scores already include 1/sqrt(dk) via prescaled Q
        f4x sc[4];
#pragma unroll
        for (int ni = 0; ni < 4; ++ni) { f4x z = {0.f, 0.f, 0.f, 0.f}; sc[ni] = z; }
        __builtin_amdgcn_s_setprio(1);
#pragma unroll
        for (int kk = 0; kk < 2; ++kk) {
#pragma unroll
            for (int ni = 0; ni < 4; ++ni) {
                int row = ni * 16 + l15;
                int cb  = (kk * 64 + lg * 16) ^ ((row & 7) << 4);
                s8x kf = *(const s8x*)((const char*)Ks[cur] + row * 128 + cb);
                sc[ni] = __builtin_amdgcn_mfma_f32_16x16x32_bf16(kf, qf[kk], sc[ni], 0, 0, 0);
            }
        }
        __builtin_amdgcn_s_setprio(0);

        // clip (clamp -> v_med3)
#pragma unroll
        for (int ni = 0; ni < 4; ++ni)
#pragma unroll
            for (int r = 0; r < 4; ++r)
                sc[ni][r] = fminf(fmaxf(sc[ni][r], -30.f), 30.f);
        if (am) {
            int qg = qt * 128 + wid * 16 + l15;
#pragma unroll
            for (int ni = 0; ni < 4; ++ni)
#pragma unroll
                for (int r = 0; r < 4; ++r) {
                    int kcol = kt * 64 + ni * 16 + lg * 4 + r;
                    u32 wb_ = maskw[(rowbase + qg) * 32 + (kcol >> 5)];
                    if (wb_ & (1u << (kcol & 31))) sc[ni][r] = -1e9f;
                }
        }

        // online softmax with defer-max (T13, THR=8)
        float mx = fmaxf(fmaxf(fmaxf(sc[0][0], sc[0][1]), fmaxf(sc[0][2], sc[0][3])),
                         fmaxf(fmaxf(sc[1][0], sc[1][1]), fmaxf(sc[1][2], sc[1][3])));
        mx = fmaxf(mx, fmaxf(fmaxf(fmaxf(sc[2][0], sc[2][1]), fmaxf(sc[2][2], sc[2][3])),
                             fmaxf(fmaxf(sc[3][0], sc[3][1]), fmaxf(sc[3][2], sc[3][3]))));
        mx = fmaxf(mx, __shfl_xor(mx, 16));
        mx = fmaxf(mx, __shfl_xor(mx, 32));
        if (!__all(mx <= mrun + 8.f)) {     // defer: only rescale on big max growth
            float mn = fmaxf(mrun, mx);
            float al = __expf(mrun - mn);
            mrun = mn;
            lrun *= al;
#pragma unroll
            for (int r = 0; r < 4; ++r) {
                float alr = __shfl(al, lg * 4 + r);
#pragma unroll
                for (int d = 0; d < 4; ++d) o[d][r] *= alr;
            }
        }
        float s = 0.f;
#pragma unroll
        for (int ni = 0; ni < 4; ++ni)
#pragma unroll
            for (int r = 0; r < 4; ++r) {
                float p = __expf(sc[ni][r] - mrun);   // bounded by e^8
                sc[ni][r] = p;
                s += p;
            }
        s += __shfl_xor(s, 16);
        s += __shfl_xor(s, 32);
        lrun += s;

#pragma unroll
        for (int ni = 0; ni < 4; ++ni) {
            uint2 w; w.x = pk2(sc[ni][0], sc[ni][1]); w.y = pk2(sc[ni][2], sc[ni][3]);
            *(uint2*)((char*)&Ps[wid][l15][0] + ((ni * 32 + lg * 8) ^ vswz)) = w;
        }
        s8x pa[2];
#pragma unroll
        for (int kk = 0; kk < 2; ++kk)
            pa[kk] = *(const s8x*)((const char*)&Ps[wid][l15][0] + ((kk * 64 + lg * 16) ^ vswz));

        __builtin_amdgcn_s_setprio(1);
#pragma unroll
        for (int dt = 0; dt < 4; ++dt)
#pragma unroll
            for (int kk = 0; kk < 2; ++kk) {
                int row = dt * 16 + l15;
                int cb  = (kk * 64 + lg * 16) ^ ((row & 7) << 4);
                s8x vf = *(const s8x*)((const char*)Vs[cur] + row * 128 + cb);
                o[dt] = __builtin_amdgcn_mfma_f32_16x16x32_bf16(pa[kk], vf, o[dt], 0, 0, 0);
            }
        __builtin_amdgcn_s_setprio(0);

        __syncthreads();
        cur ^= 1;
    }

    float rl = 1.f / lrun;
    float rlr[4];
#pragma unroll
    for (int r = 0; r < 4; ++r) rlr[r] = __shfl(rl, lg * 4 + r);
#pragma unroll
    for (int dt = 0; dt < 4; ++dt) {
        int gc = hoff + dt * 16 + l15;
#pragma unroll
        for (int r = 0; r < 4; ++r) {
            int gr = qt * 128 + wid * 16 + lg * 4 + r;
            Om[(rowbase + gr) * 1024 + gc] = f2b(o[dt][r] * rlr[r]);
        }
    }
}

// ---------------- LayerNorm over D=1024, one wave per row, dual bf16/f32 output ----------------
__global__ __launch_bounds__(256) void ln_kernel(
    const float* __restrict__ x, const float* __restrict__ g, const float* __restrict__ bb,
    u16* __restrict__ yb, float* __restrict__ yf)
{
    const int wid = threadIdx.x >> 6, lane = threadIdx.x & 63;
    const size_t row = (size_t)blockIdx.x * 4 + wid;
    const float* xr = x + row * 1024;
    float4 v[4];
    float s = 0.f, s2 = 0.f;
#pragma unroll
    for (int c = 0; c < 4; ++c) {
        v[c] = *(const float4*)(xr + c * 256 + lane * 4);
        s  += v[c].x + v[c].y + v[c].z + v[c].w;
        s2 += v[c].x * v[c].x + v[c].y * v[c].y + v[c].z * v[c].z + v[c].w * v[c].w;
    }
#pragma unroll
    for (int m = 32; m >= 1; m >>= 1) { s += __shfl_xor(s, m); s2 += __shfl_xor(s2, m); }
    float mean = s * (1.f / 1024.f);
    float var  = s2 * (1.f / 1024.f) - mean * mean;
    float rs = rsqrtf(var + 1e-8f);
#pragma unroll
    for (int c = 0; c < 4; ++c) {
        int col = c * 256 + lane * 4;
        float4 gv = *(const float4*)(g + col);
        float4 bv = *(const float4*)(bb + col);
        float y0 = (v[c].x - mean) * rs * gv.x + bv.x;
        float y1 = (v[c].y - mean) * rs * gv.y + bv.y;
        float y2 = (v[c].z - mean) * rs * gv.z + bv.z;
        float y3 = (v[c].w - mean) * rs * gv.w + bv.w;
        if (yb) { ushort4 o4 = make_ushort4(f2b(y0), f2b(y1), f2b(y2), f2b(y3));
                  *(ushort4*)(yb + row * 1024 + col) = o4; }
        if (yf) { float4 o4f = make_float4(y0, y1, y2, y3);
                  *(float4*)(yf + row * 1024 + col) = o4f; }
    }
}

// ---------------- f32 -> bf16 convert ----------------
__global__ __launch_bounds__(256) void cvt_kernel(const float* __restrict__ x, u16* __restrict__ y, int n4)
{
    int i = blockIdx.x * 256 + threadIdx.x;
    if (i < n4) {
        float4 v = *(const float4*)(x + (size_t)i * 4);
        ushort4 o = make_ushort4(f2b(v.x), f2b(v.y), f2b(v.z), f2b(v.w));
        *(ushort4*)(y + (size_t)i * 4) = o;
    }
}

// ---------------- transpose-convert: Y[l][i][j] = bf16(X[l][j][i]), 1024x1024/layer ----------------
__global__ __launch_bounds__(256) void cvtT_kernel(const float* __restrict__ X, u16* __restrict__ Y)
{
    __shared__ u16 T[64][65];
    const int l = blockIdx.z;
    const int j0 = blockIdx.y * 64;   // row range of X
    const int i0 = blockIdx.x * 64;   // col range of X
    const float* Xl = X + (size_t)l * 1024 * 1024;
    u16* Yl = Y + (size_t)l * 1024 * 1024;
    const int tr = threadIdx.x >> 4;
    const int tc = threadIdx.x & 15;
#pragma unroll
    for (int k = 0; k < 4; ++k) {
        int j = tr + k * 16;
        float4 v = *(const float4*)(Xl + (size_t)(j0 + j) * 1024 + i0 + tc * 4);
        T[tc * 4 + 0][j] = f2b(v.x);
        T[tc * 4 + 1][j] = f2b(v.y);
        T[tc * 4 + 2][j] = f2b(v.z);
        T[tc * 4 + 3][j] = f2b(v.w);
    }
    __syncthreads();
    const int wr_ = threadIdx.x >> 3;
    const int wc_ = threadIdx.x & 7;
#pragma unroll
    for (int k = 0; k < 2; ++k) {
        int i = wr_ + k * 32;
        u16 tmp[8];
#pragma unroll
        for (int e = 0; e < 8; ++e) tmp[e] = T[i][wc_ * 8 + e];
        *(ushort4*)(Yl + (size_t)(i0 + i) * 1024 + j0 + wc_ * 8)     = make_ushort4(tmp[0], tmp[1], tmp[2], tmp[3]);
        *(ushort4*)(Yl + (size_t)(i0 + i) * 1024 + j0 + wc_ * 8 + 4) = make_ushort4(tmp[4], tmp[5], tmp[6], tmp[7]);
    }
}

// ---------------- bcomb[l][o] = sum_j Wc2[l][o][j]*bc1[l][j] + bc2[l][o] (f32) ----------------
__global__ __launch_bounds__(256) void matvec_kernel(const float* __restrict__ W2, const float* __restrict__ b1,
                                                     const float* __restrict__ b2, float* __restrict__ outv)
{
    const int wid = threadIdx.x >> 6, lane = threadIdx.x & 63;
    int row = blockIdx.x * 4 + wid;           // 0..2047
    int l = row >> 10, o = row & 1023;
    const float* wr_ = W2 + (size_t)l * 1024 * 1024 + (size_t)o * 1024;
    const float* b1l = b1 + l * 1024;
    float s = 0.f;
#pragma unroll
    for (int c = 0; c < 4; ++c) {
        float4 w = *(const float4*)(wr_ + c * 256 + lane * 4);
        float4 bv = *(const float4*)(b1l + c * 256 + lane * 4);
        s += w.x * bv.x + w.y * bv.y + w.z * bv.z + w.w * bv.w;
    }
#pragma unroll
    for (int m = 32; m >= 1; m >>= 1) s += __shfl_xor(s, m);
    if (lane == 0) outv[row] = s + b2[l * 1024 + o];
}

// ---------------- mask bitpack + per-row any-flag ----------------
__global__ __launch_bounds__(256) void mask_kernel(const int* __restrict__ am, u32* __restrict__ mw)
{
    size_t idx = (size_t)blockIdx.x * 256 + threadIdx.x;
    unsigned long long bal = __ballot(am[idx] == 0);
    int lane = threadIdx.x & 63;
    if (lane == 0)  mw[idx >> 5] = (u32)bal;
    if (lane == 32) mw[idx >> 5] = (u32)(bal >> 32);
}

__global__ __launch_bounds__(256) void rowflag_kernel(const u32* __restrict__ mw, u32* __restrict__ rf)
{
    int r = blockIdx.x * 256 + threadIdx.x;
    u32 o = 0;
#pragma unroll
    for (int i = 0; i < 32; ++i) o |= mw[r * 32 + i];
    rf[r] = o;
}

// ---------------- host-side orchestration ----------------
extern "C" void kernel_launch(void* const* d_in, const int* in_sizes, int n_in,
                              void* d_out, int out_size, void* d_ws, size_t ws_size,
                              hipStream_t stream)
{
    (void)in_sizes; (void)n_in; (void)out_size; (void)ws_size;

    const float* q_in  = (const float*)d_in[0];
    const float* k_in  = (const float*)d_in[1];
    const float* v_in  = (const float*)d_in[2];
    const int*   amask = (const int*)d_in[3];
    const float* Wqkv  = (const float*)d_in[4];
    const float* bqkv  = (const float*)d_in[5];
    const float* Wo    = (const float*)d_in[6];
    const float* bo    = (const float*)d_in[7];
    const float* ln1g  = (const float*)d_in[8];
    const float* ln1b  = (const float*)d_in[9];
    const float* ln2g  = (const float*)d_in[10];
    const float* ln2b  = (const float*)d_in[11];
    const float* Wc1   = (const float*)d_in[12];
    const float* bc1   = (const float*)d_in[13];
    const float* Wc2   = (const float*)d_in[14];
    const float* bc2   = (const float*)d_in[15];
    const float* lastg = (const float*)d_in[16];
    const float* lastb = (const float*)d_in[17];
    const float* Wfc   = (const float*)d_in[18];
    const float* bfc   = (const float*)d_in[19];
    float* out = (float*)d_out;

    char* base = (char*)d_ws;
    size_t off = 0;
    auto alloc = [&](size_t bytes) -> char* {
        char* p = base + off;
        off = (off + bytes + 255) & ~(size_t)255;
        return p;
    };
    const size_t M1 = 1024 * 1024;          // D*D
    const size_t MT = 8192 * 1024;          // B*S*D
    u16* wqkv_b = (u16*)alloc(6 * M1 * 2);
    u16* wo_b   = (u16*)alloc(2 * M1 * 2);
    u16* wcomb  = (u16*)alloc(2 * M1 * 2);  // (Wc2*Wc1) per layer
    u16* wfc_b  = (u16*)alloc(M1 * 2);
    float* bcomb = (float*)alloc(2 * 1024 * 4);
    float* zb    = (float*)alloc(1024 * 4); // zero bias
    u32* maskw  = (u32*)alloc(8192 * 32 * 4);
    u32* rowfl  = (u32*)alloc(8192 * 4);
    float* sF   = (float*)alloc(MT * 4);
    float* sT   = (float*)alloc(MT * 4);
    u16* t0 = (u16*)alloc(MT * 2);
    u16* qh = (u16*)alloc(MT * 2);
    u16* kh = (u16*)alloc(MT * 2);
    u16* vt = (u16*)alloc(MT * 2);          // V^T: [1024 d_global][8192 s_global]
    u16* xb = (u16*)alloc(MT * 2);          // LN2-out bf16 (and layer-1 v_in cvt)
    u16* x2 = (u16*)alloc(MT * 2);          // bf16 state (and layer-1 k_in cvt)
    // prep-phase scratch aliases (consumed before qh/kh are first written):
    u16* wc1t  = qh;                        // Wc1^T bf16, 2*M1
    u16* wc2_b = kh;                        // Wc2 bf16, 2*M1

    // ---- weight prep ----
    cvt_kernel<<<6 * M1 / 1024, 256, 0, stream>>>(Wqkv, wqkv_b, (int)(6 * M1 / 4));
    cvt_kernel<<<2 * M1 / 1024, 256, 0, stream>>>(Wo,   wo_b,   (int)(2 * M1 / 4));
    cvt_kernel<<<M1 / 1024, 256, 0, stream>>>(Wfc, wfc_b, (int)(M1 / 4));
    cvt_kernel<<<2 * M1 / 1024, 256, 0, stream>>>(Wc2, wc2_b, (int)(2 * M1 / 4));
    cvtT_kernel<<<dim3(16, 16, 2), 256, 0, stream>>>(Wc1, wc1t);
    hipMemsetAsync(zb, 0, 1024 * 4, stream);
    // Wcomb[l] = Wc2[l] @ Wc1[l]  (C[o,i] = sum_j Wc2[o,j] * Wc1T[i,j])
    gemm_z2<<<dim3(8, 8, 2), 256, 0, stream>>>(
        wc2_b, wc1t, zb, wcomb, 1.f,
        wc2_b + M1, wc1t + M1, zb, wcomb + M1, 1.f);
    matvec_kernel<<<512, 256, 0, stream>>>(Wc2, bc1, bc2, bcomb);
    mask_kernel<<<32768, 256, 0, stream>>>(amask, maskw);
    rowflag_kernel<<<32, 256, 0, stream>>>(maskw, rowfl);

    dim3 ggrid(8192 / BM, 1024 / BN);   // (64, 8)
    dim3 vgrid(1024 / BM, 8192 / BN);   // (8, 64) swapped V-projection
    const int D = 1024;
    for (int i = 0; i < 2; ++i) {
        const float* qsrc = (i == 0) ? q_in : sF;
        // LN1(q) -> t0 (bf16)
        ln_kernel<<<2048, 256, 0, stream>>>(qsrc, ln1g + i * D, ln1b + i * D, t0, nullptr);
        if (i == 0) {
            cvt_kernel<<<8192, 256, 0, stream>>>(k_in, x2, (int)(MT / 4));
            cvt_kernel<<<8192, 256, 0, stream>>>(v_in, xb, (int)(MT / 4));
        }
        // Q (prescaled by 1/8) + K projections, one dispatch
        gemm_z2<<<dim3(64, 8, 2), 256, 0, stream>>>(
            t0, wqkv_b + (size_t)(i * 3 + 0) * M1, bqkv + (i * 3 + 0) * D, qh, 0.125f,
            x2, wqkv_b + (size_t)(i * 3 + 1) * M1, bqkv + (i * 3 + 1) * D, kh, 1.f);
        // V projection, swapped: vt[d][s] = W_v · X^T  (row-bias)
        const u16* vin_b = (i == 0) ? xb : x2;
        gemm_bt<8 | 16, 8192><<<vgrid, 256, 0, stream>>>(wqkv_b + (size_t)(i * 3 + 2) * M1, vin_b,
                                              bqkv + (i * 3 + 2) * D, nullptr, nullptr, vt);
        // attention -> t0
        attn_kernel<<<dim3(128, 8), 512, 0, stream>>>(qh, kh, vt, maskw, rowfl, t0);
        // x = relu(attn @ Wo^T + bo); sT = residual + x   (f32)
        const float* resp = (i == 0) ? k_in : sF;
        gemm_bt<1 | 2 | 4, 1024><<<ggrid, 256, 0, stream>>>(t0, wo_b + (size_t)i * M1,
                                                      bo + i * D, resp, sT, nullptr);
        // k1 = LN2(sT) -> sF (f32) + xb (bf16)
        ln_kernel<<<2048, 256, 0, stream>>>(sT, ln2g + i * D, ln2b + i * D, xb, sF);
        // folded FFN: k2 = k1 + k1 @ Wcomb^T + bcomb -> sT (f32) + x2 (bf16)
        gemm_bt<2 | 4 | 8, 1024><<<ggrid, 256, 0, stream>>>(xb, wcomb + (size_t)i * M1,
                                                      bcomb + i * 1024, sF, sT, x2);
        // new state: f32 in sT (swap), bf16 in x2
        float* tmp = sF; sF = sT; sT = tmp;
    }
    // final LN + FC
    ln_kernel<<<2048, 256, 0, stream>>>(sF, lastg, lastb, t0, nullptr);
    gemm_bt<4, 1024><<<ggrid, 256, 0, stream>>>(t0, wfc_b, bfc, nullptr, out, nullptr);
}

// Round 6
// 560.289 us; speedup vs baseline: 1.6540x; 1.2409x over previous
//
#include <hip/hip_runtime.h>

typedef __attribute__((ext_vector_type(8))) short s8x;   // 8 x bf16 (raw bits)
typedef __attribute__((ext_vector_type(4))) float f4x;
typedef unsigned short u16;
typedef unsigned int u32;

#define DEV static __device__ __forceinline__

DEV u16 f2b(float f) {
    union { float f; u32 u; } v; v.f = f;
    u32 r = v.u + 0x7FFFu + ((v.u >> 16) & 1u);
    return (u16)(r >> 16);
}

DEV u32 pk2(float lo, float hi) {   // v_cvt_pk_bf16_f32: low16=lo, high16=hi
    u32 r;
    asm("v_cvt_pk_bf16_f32 %0, %1, %2" : "=v"(r) : "v"(lo), "v"(hi));
    return r;
}

DEV void gload16(const void* g, void* lds) {
    __builtin_amdgcn_global_load_lds(
        (const __attribute__((address_space(1))) void*)g,
        (__attribute__((address_space(3))) void*)lds, 16, 0, 0);
}

#define GK 1024
#define BM 128
#define BN 128
#define BK 64

// ---------------- 8-phase GEMM: C[M,N] = A[M,K] @ W[N,K]^T, 256x128 tile ----------------
// 8 waves (4M x 2N), BK=64, 3-deep LDS buffers (A 32KB + B 16KB per tile, 144KB total).
// Counted vmcnt(6) main loop (T4), raw s_barrier (no compiler drain), XOR-swizzled LDS (T2),
// setprio around MFMA clusters (T5). K = 1024 fixed (16 K-tiles).
// Swizzle (both-sides, rule #21): LDS[row][cd] = G[row][cd ^ (row&7)]; read chunk = want ^ (row&7).

DEV void stage_unit(const u16* __restrict__ g, char* l, int tid) {
    // one 16KB unit = 128 rows x 128B; 512 threads x 2 x 16B
#pragma unroll
    for (int i = 0; i < 2; ++i) {
        int db = i * 8192 + tid * 16;
        int row = db >> 7;
        int cs = ((db >> 4) & 7) ^ (row & 7);
        gload16(g + (size_t)row * 1024 + cs * 8, l + db);
    }
}

DEV s8x lds_frag(const char* Lbase, int row, int kk, int lg) {
    int cb = (kk * 64 + lg * 16) ^ ((row & 7) << 4);
    return *(const s8x*)(Lbase + row * 128 + cb);
}

template<int FLAGS, int NN>
__global__ __launch_bounds__(512, 2) void gemm8(
    const u16* __restrict__ A, const u16* __restrict__ W,
    const float* __restrict__ bias, const float* __restrict__ res,
    float* __restrict__ outf, u16* __restrict__ outb, float scl)
{
    constexpr bool RELU = (FLAGS & 1) != 0;
    constexpr bool RES  = (FLAGS & 2) != 0;
    constexpr bool WF   = (FLAGS & 4) != 0;
    constexpr bool WB   = (FLAGS & 8) != 0;
    constexpr bool RBIA = (FLAGS & 16) != 0;

    __shared__ __attribute__((aligned(16))) u16 As[3][256 * 64];   // 96 KB
    __shared__ __attribute__((aligned(16))) u16 Bs[3][128 * 64];   // 48 KB

    const int tid = threadIdx.x, lane = tid & 63, wid = tid >> 6;
    const int l15 = lane & 15, lg = lane >> 4;
    const int wm = wid >> 1, wn = wid & 1;
    const int bm = blockIdx.x, bn = blockIdx.y;

    const u16* Ab = A + (size_t)bm * 256 * GK;
    const u16* Wb = W + (size_t)bn * 128 * GK;

    f4x acc[4][4];
#pragma unroll
    for (int i = 0; i < 4; ++i)
#pragma unroll
        for (int j = 0; j < 4; ++j) { f4x z = {0.f, 0.f, 0.f, 0.f}; acc[i][j] = z; }

    char* a0 = (char*)As[0]; char* a1 = (char*)As[1]; char* a2 = (char*)As[2];
    char* b0 = (char*)Bs[0]; char* b1 = (char*)Bs[1]; char* b2 = (char*)Bs[2];

    // prologue: stage tiles 0 and 1 (6 loads each)
    stage_unit(Ab + 0 * 64,                 a0,        tid);
    stage_unit(Ab + 128 * GK + 0 * 64,      a0 + 16384, tid);
    stage_unit(Wb + 0 * 64,                 b0,        tid);
    stage_unit(Ab + 1 * 64,                 a1,        tid);
    stage_unit(Ab + 128 * GK + 1 * 64,      a1 + 16384, tid);
    stage_unit(Wb + 1 * 64,                 b1,        tid);
    asm volatile("s_waitcnt vmcnt(6)" ::: "memory");
    __builtin_amdgcn_s_barrier();

    for (int t = 0; t < 16; ++t) {
        const bool st = (t < 14);
        // ---- phase 0: B all + A(mi 0,1); stage A-units of t+2; MFMA mi 0,1 ----
        s8x bfr[4][2], afr[2][2];
#pragma unroll
        for (int ni = 0; ni < 4; ++ni)
#pragma unroll
            for (int kk = 0; kk < 2; ++kk)
                bfr[ni][kk] = lds_frag(b0, wn * 64 + ni * 16 + l15, kk, lg);
#pragma unroll
        for (int mi = 0; mi < 2; ++mi)
#pragma unroll
            for (int kk = 0; kk < 2; ++kk)
                afr[mi][kk] = lds_frag(a0, wm * 64 + mi * 16 + l15, kk, lg);
        if (st) {
            stage_unit(Ab + (t + 2) * 64,            a2,         tid);
            stage_unit(Ab + 128 * GK + (t + 2) * 64, a2 + 16384, tid);
        }
        __builtin_amdgcn_s_barrier();
        asm volatile("s_waitcnt lgkmcnt(0)" ::: "memory");
        __builtin_amdgcn_sched_barrier(0);
        __builtin_amdgcn_s_setprio(1);
#pragma unroll
        for (int kk = 0; kk < 2; ++kk)
#pragma unroll
            for (int mi = 0; mi < 2; ++mi)
#pragma unroll
                for (int ni = 0; ni < 4; ++ni)
                    acc[mi][ni] = __builtin_amdgcn_mfma_f32_16x16x32_bf16(afr[mi][kk], bfr[ni][kk], acc[mi][ni], 0, 0, 0);
        __builtin_amdgcn_s_setprio(0);
        __builtin_amdgcn_s_barrier();

        // ---- phase 1: A(mi 2,3); stage B-unit of t+2; MFMA mi 2,3 ----
        s8x afr2[2][2];
#pragma unroll
        for (int mi = 0; mi < 2; ++mi)
#pragma unroll
            for (int kk = 0; kk < 2; ++kk)
                afr2[mi][kk] = lds_frag(a0, wm * 64 + (mi + 2) * 16 + l15, kk, lg);
        if (st) stage_unit(Wb + (t + 2) * 64, b2, tid);
        __builtin_amdgcn_s_barrier();
        asm volatile("s_waitcnt lgkmcnt(0)" ::: "memory");
        __builtin_amdgcn_sched_barrier(0);
        __builtin_amdgcn_s_setprio(1);
#pragma unroll
        for (int kk = 0; kk < 2; ++kk)
#pragma unroll
            for (int mi = 0; mi < 2; ++mi)
#pragma unroll
                for (int ni = 0; ni < 4; ++ni)
                    acc[mi + 2][ni] = __builtin_amdgcn_mfma_f32_16x16x32_bf16(afr2[mi][kk], bfr[ni][kk], acc[mi + 2][ni], 0, 0, 0);
        __builtin_amdgcn_s_setprio(0);
        // end-of-tile: ensure t+1 fully staged (counted — t+2's 6 loads stay in flight)
        if (st) asm volatile("s_waitcnt vmcnt(6)" ::: "memory");
        else    asm volatile("s_waitcnt vmcnt(0)" ::: "memory");
        __builtin_amdgcn_s_barrier();

        char* tA = a0; a0 = a1; a1 = a2; a2 = tA;
        char* tB = b0; b0 = b1; b1 = b2; b2 = tB;
    }

    // epilogue: C/D layout col=lane&15, row=(lane>>4)*4+r
#pragma unroll
    for (int ni = 0; ni < 4; ++ni) {
        int gcol = bn * 128 + wn * 64 + ni * 16 + l15;
        float bvc = RBIA ? 0.f : bias[gcol];
#pragma unroll
        for (int mi = 0; mi < 4; ++mi) {
            int grow0 = bm * 256 + wm * 64 + mi * 16 + lg * 4;
#pragma unroll
            for (int r = 0; r < 4; ++r) {
                float bv = RBIA ? bias[grow0 + r] : bvc;
                float v = (acc[mi][ni][r] + bv) * scl;
                if (RELU) v = fmaxf(v, 0.f);
                size_t oidx = (size_t)(grow0 + r) * NN + gcol;
                if (RES) v += res[oidx];
                if (WF) outf[oidx] = v;
                if (WB) outb[oidx] = f2b(v);
            }
        }
    }
}

// ---- z-batched 2-phase variant (weight-prep only): out = f2b((acc + bias) * scl) ----
__global__ __launch_bounds__(256) void gemm_z2(
    const u16* __restrict__ A0, const u16* __restrict__ W0, const float* __restrict__ b0,
    u16* __restrict__ o0, float s0,
    const u16* __restrict__ A1, const u16* __restrict__ W1, const float* __restrict__ b1,
    u16* __restrict__ o1, float s1)
{
    const int z = blockIdx.z;
    const u16* A = z ? A1 : A0;
    const u16* W = z ? W1 : W0;
    const float* bias = z ? b1 : b0;
    u16* outb = z ? o1 : o0;
    const float scl = z ? s1 : s0;

    __shared__ __attribute__((aligned(16))) u16 As[2][BM * BK];
    __shared__ __attribute__((aligned(16))) u16 Bs[2][BN * BK];

    const int tid  = threadIdx.x;
    const int lane = tid & 63;
    const int wid  = tid >> 6;
    const int wr = wid >> 1, wc = wid & 1;
    const int bm = blockIdx.x, bn = blockIdx.y;
    const int l15 = lane & 15;
    const int lg  = lane >> 4;

    const u16* Ab = A + (size_t)bm * BM * GK;
    const u16* Wb = W + (size_t)bn * BN * GK;

    const int prow = tid >> 3;
    const int pcol = (tid & 7) * 8;

    f4x acc[4][4];
#pragma unroll
    for (int i = 0; i < 4; ++i)
#pragma unroll
        for (int j = 0; j < 4; ++j) { f4x z_ = {0.f, 0.f, 0.f, 0.f}; acc[i][j] = z_; }

#pragma unroll
    for (int c = 0; c < 4; ++c) {
        int row = c * 32 + prow;
        gload16(Ab + (size_t)row * GK + pcol, &As[0][row * BK + pcol]);
    }
#pragma unroll
    for (int c = 0; c < 4; ++c) {
        int row = c * 32 + prow;
        gload16(Wb + (size_t)row * GK + pcol, &Bs[0][row * BK + pcol]);
    }

    const int nkt = GK / BK;
    int cur = 0;
    for (int kt = 0; kt < nkt; ++kt) {
        __syncthreads();
        if (kt + 1 < nkt) {
            const u16* Ak = Ab + (kt + 1) * BK;
            const u16* Wk = Wb + (kt + 1) * BK;
#pragma unroll
            for (int c = 0; c < 4; ++c) {
                int row = c * 32 + prow;
                gload16(Ak + (size_t)row * GK + pcol, &As[cur ^ 1][row * BK + pcol]);
            }
#pragma unroll
            for (int c = 0; c < 4; ++c) {
                int row = c * 32 + prow;
                gload16(Wk + (size_t)row * GK + pcol, &Bs[cur ^ 1][row * BK + pcol]);
            }
        }
        const u16* Ac = As[cur];
        const u16* Bc = Bs[cur];
#pragma unroll
        for (int kk = 0; kk < 2; ++kk) {
            s8x a[4], b[4];
#pragma unroll
            for (int mi = 0; mi < 4; ++mi)
                a[mi] = *(const s8x*)(Ac + (wr * 64 + mi * 16 + l15) * BK + kk * 32 + lg * 8);
#pragma unroll
            for (int ni = 0; ni < 4; ++ni)
                b[ni] = *(const s8x*)(Bc + (wc * 64 + ni * 16 + l15) * BK + kk * 32 + lg * 8);
#pragma unroll
            for (int mi = 0; mi < 4; ++mi)
#pragma unroll
                for (int ni = 0; ni < 4; ++ni)
                    acc[mi][ni] = __builtin_amdgcn_mfma_f32_16x16x32_bf16(a[mi], b[ni], acc[mi][ni], 0, 0, 0);
        }
        cur ^= 1;
    }

#pragma unroll
    for (int ni = 0; ni < 4; ++ni) {
        int gcol = bn * BN + wc * 64 + ni * 16 + l15;
        float bvc = bias[gcol];
#pragma unroll
        for (int mi = 0; mi < 4; ++mi) {
            int grow0 = bm * BM + wr * 64 + mi * 16 + lg * 4;
#pragma unroll
            for (int r = 0; r < 4; ++r) {
                float v = (acc[mi][ni][r] + bvc) * scl;
                outb[(size_t)(grow0 + r) * 1024 + gcol] = f2b(v);
            }
        }
    }
}

// ---------------- Attention: QBLK=128, 8 waves, prescaled Q, defer-max THR=8 ----------------
__global__ __launch_bounds__(512) void attn_kernel(
    const u16* __restrict__ Qm, const u16* __restrict__ Km, const u16* __restrict__ Vt,
    const u32* __restrict__ maskw, const u32* __restrict__ rowfl,
    u16* __restrict__ Om)
{
    const int bh = blockIdx.x;
    const int b  = bh >> 4;
    const int h  = bh & 15;
    const int qt = blockIdx.y;
    const int tid = threadIdx.x, lane = tid & 63, wid = tid >> 6;
    const int l15 = lane & 15, lg = lane >> 4;

    __shared__ __attribute__((aligned(16))) u16 Ks[2][64 * 64];
    __shared__ __attribute__((aligned(16))) u16 Vs[2][64 * 64];
    __shared__ __attribute__((aligned(16))) u16 Ps[8][16][64];
    __shared__ int anymask;

    const size_t rowbase = (size_t)b * 1024;
    const int hoff = h * 64;

    if (tid == 0) anymask = 0;

    const int so   = tid * 16;
    const int srow = so >> 7;
    const int sch  = ((so >> 4) & 7) ^ (srow & 7);
    const int vswz = (l15 & 7) << 4;

    const u16* Kbase = Km + rowbase * 1024 + hoff;
    const u16* Vbase = Vt + (size_t)(hoff + srow) * 8192 + b * 1024;

    gload16(Kbase + (size_t)srow * 1024 + sch * 8, (char*)Ks[0] + so);
    gload16(Vbase + sch * 8,                       (char*)Vs[0] + so);

    __syncthreads();
    if (tid < 128) {
        if (rowfl[rowbase + qt * 128 + tid]) atomicOr(&anymask, 1);
    }

    const int qrow = qt * 128 + wid * 16 + l15;
    s8x qf[2];
#pragma unroll
    for (int kk = 0; kk < 2; ++kk)
        qf[kk] = *(const s8x*)(Qm + (rowbase + qrow) * 1024 + hoff + kk * 32 + lg * 8);

    f4x o[4];
#pragma unroll
    for (int d = 0; d < 4; ++d) { f4x z = {0.f, 0.f, 0.f, 0.f}; o[d] = z; }
    float mrun = -1e30f, lrun = 0.f;

    __syncthreads();
    const int am = anymask;

    int cur = 0;
    for (int kt = 0; kt < 16; ++kt) {
        if (kt < 15) {
            gload16(Kbase + (size_t)(kt + 1) * 64 * 1024 + (size_t)srow * 1024 + sch * 8,
                    (char*)Ks[cur ^ 1] + so);
            gload16(Vbase + (kt + 1) * 64 + sch * 8, (char*)Vs[cur ^ 1] + so);
        }

        f4x sc[4];
#pragma unroll
        for (int ni = 0; ni < 4; ++ni) { f4x z = {0.f, 0.f, 0.f, 0.f}; sc[ni] = z; }
        __builtin_amdgcn_s_setprio(1);
#pragma unroll
        for (int kk = 0; kk < 2; ++kk) {
#pragma unroll
            for (int ni = 0; ni < 4; ++ni) {
                int row = ni * 16 + l15;
                int cb  = (kk * 64 + lg * 16) ^ ((row & 7) << 4);
                s8x kf = *(const s8x*)((const char*)Ks[cur] + row * 128 + cb);
                sc[ni] = __builtin_amdgcn_mfma_f32_16x16x32_bf16(kf, qf[kk], sc[ni], 0, 0, 0);
            }
        }
        __builtin_amdgcn_s_setprio(0);

#pragma unroll
        for (int ni = 0; ni < 4; ++ni)
#pragma unroll
            for (int r = 0; r < 4; ++r)
                sc[ni][r] = fminf(fmaxf(sc[ni][r], -30.f), 30.f);
        if (am) {
            int qg = qt * 128 + wid * 16 + l15;
#pragma unroll
            for (int ni = 0; ni < 4; ++ni)
#pragma unroll
                for (int r = 0; r < 4; ++r) {
                    int kcol = kt * 64 + ni * 16 + lg * 4 + r;
                    u32 wb_ = maskw[(rowbase + qg) * 32 + (kcol >> 5)];
                    if (wb_ & (1u << (kcol & 31))) sc[ni][r] = -1e9f;
                }
        }

        float mx = fmaxf(fmaxf(fmaxf(sc[0][0], sc[0][1]), fmaxf(sc[0][2], sc[0][3])),
                         fmaxf(fmaxf(sc[1][0], sc[1][1]), fmaxf(sc[1][2], sc[1][3])));
        mx = fmaxf(mx, fmaxf(fmaxf(fmaxf(sc[2][0], sc[2][1]), fmaxf(sc[2][2], sc[2][3])),
                             fmaxf(fmaxf(sc[3][0], sc[3][1]), fmaxf(sc[3][2], sc[3][3]))));
        mx = fmaxf(mx, __shfl_xor(mx, 16));
        mx = fmaxf(mx, __shfl_xor(mx, 32));
        if (!__all(mx <= mrun + 8.f)) {
            float mn = fmaxf(mrun, mx);
            float al = __expf(mrun - mn);
            mrun = mn;
            lrun *= al;
#pragma unroll
            for (int r = 0; r < 4; ++r) {
                float alr = __shfl(al, lg * 4 + r);
#pragma unroll
                for (int d = 0; d < 4; ++d) o[d][r] *= alr;
            }
        }
        float s = 0.f;
#pragma unroll
        for (int ni = 0; ni < 4; ++ni)
#pragma unroll
            for (int r = 0; r < 4; ++r) {
                float p = __expf(sc[ni][r] - mrun);
                sc[ni][r] = p;
                s += p;
            }
        s += __shfl_xor(s, 16);
        s += __shfl_xor(s, 32);
        lrun += s;

#pragma unroll
        for (int ni = 0; ni < 4; ++ni) {
            uint2 w; w.x = pk2(sc[ni][0], sc[ni][1]); w.y = pk2(sc[ni][2], sc[ni][3]);
            *(uint2*)((char*)&Ps[wid][l15][0] + ((ni * 32 + lg * 8) ^ vswz)) = w;
        }
        s8x pa[2];
#pragma unroll
        for (int kk = 0; kk < 2; ++kk)
            pa[kk] = *(const s8x*)((const char*)&Ps[wid][l15][0] + ((kk * 64 + lg * 16) ^ vswz));

        __builtin_amdgcn_s_setprio(1);
#pragma unroll
        for (int dt = 0; dt < 4; ++dt)
#pragma unroll
            for (int kk = 0; kk < 2; ++kk) {
                int row = dt * 16 + l15;
                int cb  = (kk * 64 + lg * 16) ^ ((row & 7) << 4);
                s8x vf = *(const s8x*)((const char*)Vs[cur] + row * 128 + cb);
                o[dt] = __builtin_amdgcn_mfma_f32_16x16x32_bf16(pa[kk], vf, o[dt], 0, 0, 0);
            }
        __builtin_amdgcn_s_setprio(0);

        __syncthreads();
        cur ^= 1;
    }

    float rl = 1.f / lrun;
    float rlr[4];
#pragma unroll
    for (int r = 0; r < 4; ++r) rlr[r] = __shfl(rl, lg * 4 + r);
#pragma unroll
    for (int dt = 0; dt < 4; ++dt) {
        int gc = hoff + dt * 16 + l15;
#pragma unroll
        for (int r = 0; r < 4; ++r) {
            int gr = qt * 128 + wid * 16 + lg * 4 + r;
            Om[(rowbase + gr) * 1024 + gc] = f2b(o[dt][r] * rlr[r]);
        }
    }
}

// ---------------- LayerNorm over D=1024, one wave per row, dual bf16/f32 output ----------------
__global__ __launch_bounds__(256) void ln_kernel(
    const float* __restrict__ x, const float* __restrict__ g, const float* __restrict__ bb,
    u16* __restrict__ yb, float* __restrict__ yf)
{
    const int wid = threadIdx.x >> 6, lane = threadIdx.x & 63;
    const size_t row = (size_t)blockIdx.x * 4 + wid;
    const float* xr = x + row * 1024;
    float4 v[4];
    float s = 0.f, s2 = 0.f;
#pragma unroll
    for (int c = 0; c < 4; ++c) {
        v[c] = *(const float4*)(xr + c * 256 + lane * 4);
        s  += v[c].x + v[c].y + v[c].z + v[c].w;
        s2 += v[c].x * v[c].x + v[c].y * v[c].y + v[c].z * v[c].z + v[c].w * v[c].w;
    }
#pragma unroll
    for (int m = 32; m >= 1; m >>= 1) { s += __shfl_xor(s, m); s2 += __shfl_xor(s2, m); }
    float mean = s * (1.f / 1024.f);
    float var  = s2 * (1.f / 1024.f) - mean * mean;
    float rs = rsqrtf(var + 1e-8f);
#pragma unroll
    for (int c = 0; c < 4; ++c) {
        int col = c * 256 + lane * 4;
        float4 gv = *(const float4*)(g + col);
        float4 bv = *(const float4*)(bb + col);
        float y0 = (v[c].x - mean) * rs * gv.x + bv.x;
        float y1 = (v[c].y - mean) * rs * gv.y + bv.y;
        float y2 = (v[c].z - mean) * rs * gv.z + bv.z;
        float y3 = (v[c].w - mean) * rs * gv.w + bv.w;
        if (yb) { ushort4 o4 = make_ushort4(f2b(y0), f2b(y1), f2b(y2), f2b(y3));
                  *(ushort4*)(yb + row * 1024 + col) = o4; }
        if (yf) { float4 o4f = make_float4(y0, y1, y2, y3);
                  *(float4*)(yf + row * 1024 + col) = o4f; }
    }
}

// ---------------- f32 -> bf16 convert ----------------
__global__ __launch_bounds__(256) void cvt_kernel(const float* __restrict__ x, u16* __restrict__ y, int n4)
{
    int i = blockIdx.x * 256 + threadIdx.x;
    if (i < n4) {
        float4 v = *(const float4*)(x + (size_t)i * 4);
        ushort4 o = make_ushort4(f2b(v.x), f2b(v.y), f2b(v.z), f2b(v.w));
        *(ushort4*)(y + (size_t)i * 4) = o;
    }
}

// ---------------- transpose-convert: Y[l][i][j] = bf16(X[l][j][i]), 1024x1024/layer ----------------
__global__ __launch_bounds__(256) void cvtT_kernel(const float* __restrict__ X, u16* __restrict__ Y)
{
    __shared__ u16 T[64][65];
    const int l = blockIdx.z;
    const int j0 = blockIdx.y * 64;
    const int i0 = blockIdx.x * 64;
    const float* Xl = X + (size_t)l * 1024 * 1024;
    u16* Yl = Y + (size_t)l * 1024 * 1024;
    const int tr = threadIdx.x >> 4;
    const int tc = threadIdx.x & 15;
#pragma unroll
    for (int k = 0; k < 4; ++k) {
        int j = tr + k * 16;
        float4 v = *(const float4*)(Xl + (size_t)(j0 + j) * 1024 + i0 + tc * 4);
        T[tc * 4 + 0][j] = f2b(v.x);
        T[tc * 4 + 1][j] = f2b(v.y);
        T[tc * 4 + 2][j] = f2b(v.z);
        T[tc * 4 + 3][j] = f2b(v.w);
    }
    __syncthreads();
    const int wr_ = threadIdx.x >> 3;
    const int wc_ = threadIdx.x & 7;
#pragma unroll
    for (int k = 0; k < 2; ++k) {
        int i = wr_ + k * 32;
        u16 tmp[8];
#pragma unroll
        for (int e = 0; e < 8; ++e) tmp[e] = T[i][wc_ * 8 + e];
        *(ushort4*)(Yl + (size_t)(i0 + i) * 1024 + j0 + wc_ * 8)     = make_ushort4(tmp[0], tmp[1], tmp[2], tmp[3]);
        *(ushort4*)(Yl + (size_t)(i0 + i) * 1024 + j0 + wc_ * 8 + 4) = make_ushort4(tmp[4], tmp[5], tmp[6], tmp[7]);
    }
}

// ---------------- bcomb[l][o] = sum_j Wc2[l][o][j]*bc1[l][j] + bc2[l][o] (f32) ----------------
__global__ __launch_bounds__(256) void matvec_kernel(const float* __restrict__ W2, const float* __restrict__ b1,
                                                     const float* __restrict__ b2, float* __restrict__ outv)
{
    const int wid = threadIdx.x >> 6, lane = threadIdx.x & 63;
    int row = blockIdx.x * 4 + wid;
    int l = row >> 10, o = row & 1023;
    const float* wr_ = W2 + (size_t)l * 1024 * 1024 + (size_t)o * 1024;
    const float* b1l = b1 + l * 1024;
    float s = 0.f;
#pragma unroll
    for (int c = 0; c < 4; ++c) {
        float4 w = *(const float4*)(wr_ + c * 256 + lane * 4);
        float4 bv = *(const float4*)(b1l + c * 256 + lane * 4);
        s += w.x * bv.x + w.y * bv.y + w.z * bv.z + w.w * bv.w;
    }
#pragma unroll
    for (int m = 32; m >= 1; m >>= 1) s += __shfl_xor(s, m);
    if (lane == 0) outv[row] = s + b2[l * 1024 + o];
}

// ---------------- mask bitpack + per-row any-flag ----------------
__global__ __launch_bounds__(256) void mask_kernel(const int* __restrict__ am, u32* __restrict__ mw)
{
    size_t idx = (size_t)blockIdx.x * 256 + threadIdx.x;
    unsigned long long bal = __ballot(am[idx] == 0);
    int lane = threadIdx.x & 63;
    if (lane == 0)  mw[idx >> 5] = (u32)bal;
    if (lane == 32) mw[idx >> 5] = (u32)(bal >> 32);
}

__global__ __launch_bounds__(256) void rowflag_kernel(const u32* __restrict__ mw, u32* __restrict__ rf)
{
    int r = blockIdx.x * 256 + threadIdx.x;
    u32 o = 0;
#pragma unroll
    for (int i = 0; i < 32; ++i) o |= mw[r * 32 + i];
    rf[r] = o;
}

// ---------------- host-side orchestration ----------------
extern "C" void kernel_launch(void* const* d_in, const int* in_sizes, int n_in,
                              void* d_out, int out_size, void* d_ws, size_t ws_size,
                              hipStream_t stream)
{
    (void)in_sizes; (void)n_in; (void)out_size; (void)ws_size;

    const float* q_in  = (const float*)d_in[0];
    const float* k_in  = (const float*)d_in[1];
    const float* v_in  = (const float*)d_in[2];
    const int*   amask = (const int*)d_in[3];
    const float* Wqkv  = (const float*)d_in[4];
    const float* bqkv  = (const float*)d_in[5];
    const float* Wo    = (const float*)d_in[6];
    const float* bo    = (const float*)d_in[7];
    const float* ln1g  = (const float*)d_in[8];
    const float* ln1b  = (const float*)d_in[9];
    const float* ln2g  = (const float*)d_in[10];
    const float* ln2b  = (const float*)d_in[11];
    const float* Wc1   = (const float*)d_in[12];
    const float* bc1   = (const float*)d_in[13];
    const float* Wc2   = (const float*)d_in[14];
    const float* bc2   = (const float*)d_in[15];
    const float* lastg = (const float*)d_in[16];
    const float* lastb = (const float*)d_in[17];
    const float* Wfc   = (const float*)d_in[18];
    const float* bfc   = (const float*)d_in[19];
    float* out = (float*)d_out;

    char* base = (char*)d_ws;
    size_t off = 0;
    auto alloc = [&](size_t bytes) -> char* {
        char* p = base + off;
        off = (off + bytes + 255) & ~(size_t)255;
        return p;
    };
    const size_t M1 = 1024 * 1024;          // D*D
    const size_t MT = 8192 * 1024;          // B*S*D
    u16* wqkv_b = (u16*)alloc(6 * M1 * 2);
    u16* wo_b   = (u16*)alloc(2 * M1 * 2);
    u16* wcomb  = (u16*)alloc(2 * M1 * 2);  // (Wc2*Wc1) per layer
    u16* wfc_b  = (u16*)alloc(M1 * 2);
    float* bcomb = (float*)alloc(2 * 1024 * 4);
    float* zb    = (float*)alloc(1024 * 4); // zero bias
    u32* maskw  = (u32*)alloc(8192 * 32 * 4);
    u32* rowfl  = (u32*)alloc(8192 * 4);
    float* sF   = (float*)alloc(MT * 4);
    float* sT   = (float*)alloc(MT * 4);
    u16* t0 = (u16*)alloc(MT * 2);
    u16* qh = (u16*)alloc(MT * 2);
    u16* kh = (u16*)alloc(MT * 2);
    u16* vt = (u16*)alloc(MT * 2);          // V^T: [1024 d_global][8192 s_global]
    u16* xb = (u16*)alloc(MT * 2);
    u16* x2 = (u16*)alloc(MT * 2);
    // prep-phase scratch aliases (consumed before qh/kh are first written):
    u16* wc1t  = qh;                        // Wc1^T bf16, 2*M1
    u16* wc2_b = kh;                        // Wc2 bf16, 2*M1

    // ---- weight prep ----
    cvt_kernel<<<6 * M1 / 1024, 256, 0, stream>>>(Wqkv, wqkv_b, (int)(6 * M1 / 4));
    cvt_kernel<<<2 * M1 / 1024, 256, 0, stream>>>(Wo,   wo_b,   (int)(2 * M1 / 4));
    cvt_kernel<<<M1 / 1024, 256, 0, stream>>>(Wfc, wfc_b, (int)(M1 / 4));
    cvt_kernel<<<2 * M1 / 1024, 256, 0, stream>>>(Wc2, wc2_b, (int)(2 * M1 / 4));
    cvtT_kernel<<<dim3(16, 16, 2), 256, 0, stream>>>(Wc1, wc1t);
    hipMemsetAsync(zb, 0, 1024 * 4, stream);
    gemm_z2<<<dim3(8, 8, 2), 256, 0, stream>>>(
        wc2_b, wc1t, zb, wcomb, 1.f,
        wc2_b + M1, wc1t + M1, zb, wcomb + M1, 1.f);
    matvec_kernel<<<512, 256, 0, stream>>>(Wc2, bc1, bc2, bcomb);
    mask_kernel<<<32768, 256, 0, stream>>>(amask, maskw);
    rowflag_kernel<<<32, 256, 0, stream>>>(maskw, rowfl);

    dim3 g8(8192 / 256, 1024 / 128);    // (32, 8) standard
    dim3 v8(1024 / 256, 8192 / 128);    // (4, 64) swapped V-projection
    const int D = 1024;
    for (int i = 0; i < 2; ++i) {
        const float* qsrc = (i == 0) ? q_in : sF;
        // LN1(q) -> t0 (bf16)
        ln_kernel<<<2048, 256, 0, stream>>>(qsrc, ln1g + i * D, ln1b + i * D, t0, nullptr);
        if (i == 0) {
            cvt_kernel<<<8192, 256, 0, stream>>>(k_in, x2, (int)(MT / 4));
            cvt_kernel<<<8192, 256, 0, stream>>>(v_in, xb, (int)(MT / 4));
        }
        // Q (prescaled 1/8) and K projections
        gemm8<8, 1024><<<g8, 512, 0, stream>>>(t0, wqkv_b + (size_t)(i * 3 + 0) * M1,
                                               bqkv + (i * 3 + 0) * D, nullptr, nullptr, qh, 0.125f);
        gemm8<8, 1024><<<g8, 512, 0, stream>>>(x2, wqkv_b + (size_t)(i * 3 + 1) * M1,
                                               bqkv + (i * 3 + 1) * D, nullptr, nullptr, kh, 1.f);
        // V projection, swapped: vt[d][s] = W_v · X^T  (row-bias)
        const u16* vin_b = (i == 0) ? xb : x2;
        gemm8<8 | 16, 8192><<<v8, 512, 0, stream>>>(wqkv_b + (size_t)(i * 3 + 2) * M1, vin_b,
                                                    bqkv + (i * 3 + 2) * D, nullptr, nullptr, vt, 1.f);
        // attention -> t0
        attn_kernel<<<dim3(128, 8), 512, 0, stream>>>(qh, kh, vt, maskw, rowfl, t0);
        // x = relu(attn @ Wo^T + bo); sT = residual + x   (f32)
        const float* resp = (i == 0) ? k_in : sF;
        gemm8<1 | 2 | 4, 1024><<<g8, 512, 0, stream>>>(t0, wo_b + (size_t)i * M1,
                                                       bo + i * D, resp, sT, nullptr, 1.f);
        // k1 = LN2(sT) -> sF (f32) + xb (bf16)
        ln_kernel<<<2048, 256, 0, stream>>>(sT, ln2g + i * D, ln2b + i * D, xb, sF);
        // folded FFN: k2 = k1 + k1 @ Wcomb^T + bcomb -> sT (f32) + x2 (bf16)
        gemm8<2 | 4 | 8, 1024><<<g8, 512, 0, stream>>>(xb, wcomb + (size_t)i * M1,
                                                       bcomb + i * 1024, sF, sT, x2, 1.f);
        float* tmp = sF; sF = sT; sT = tmp;
    }
    // final LN + FC
    ln_kernel<<<2048, 256, 0, stream>>>(sF, lastg, lastb, t0, nullptr);
    gemm8<4, 1024><<<g8, 512, 0, stream>>>(t0, wfc_b, bfc, nullptr, out, nullptr, 1.f);
}